// Round 1
// baseline (1024.241 us; speedup 1.0000x reference)
//
#include <hip/hip_runtime.h>
#include <cstdint>

typedef __attribute__((ext_vector_type(8))) short bf16x8;
typedef __attribute__((ext_vector_type(4))) float f32x4;

#define S_LEN 4096
#define CDIM  640
#define NPROJ 5760

__device__ __forceinline__ unsigned short f2bf(float f){
  union { float f; uint32_t u; } v; v.f = f;
  uint32_t u = v.u;
  return (unsigned short)((u + 0x7fffu + ((u >> 16) & 1u)) >> 16);
}

// ---------------- labels: nearest-resize 512x512 -> 64x64, pack m | (im==0)<<8
__global__ void k_labels(const int* __restrict__ mask, const int* __restrict__ inp,
                         int* __restrict__ labels){
  int s = blockIdx.x * 256 + threadIdx.x;
  if (s >= S_LEN) return;
  int y = s >> 6, x = s & 63;
  int off = (y * 8) * 512 + x * 8;   // floor(i*512/64) = i*8
  int m = mask[off] & 0xff;
  int o = (inp[off] == 0) ? 0x100 : 0;
  labels[s] = m | o;
}

// ---------------- f32 -> bf16 converts
__global__ void k_cvt_hs(const float* __restrict__ src, unsigned short* __restrict__ dst, int n){
  int idx = (blockIdx.x * 256 + threadIdx.x) * 4;
  if (idx >= n) return;
  float4 v = *(const float4*)(src + idx);
  ushort4 o;
  o.x = f2bf(v.x); o.y = f2bf(v.y); o.z = f2bf(v.z); o.w = f2bf(v.w);
  *(ushort4*)(dst + idx) = o;
}

struct WPtrs { const float* w[10]; };

__global__ void k_cvt_w(WPtrs p, unsigned short* __restrict__ dst){
  int e = (blockIdx.x * 256 + threadIdx.x) * 4;
  if (e >= 10 * 409600) return;
  int a = e / 409600, r = e % 409600;
  // fold softmax 1/sqrt(d) into Q-projection weights
  float sc = (a == 0 || a == 6) ? 0.11180339887498948f   // 1/sqrt(80)
           : (a == 3 ? 0.03952847075210474f : 1.0f);     // 1/sqrt(640)
  float4 v = *(const float4*)(p.w[a] + r);
  ushort4 o;
  o.x = f2bf(v.x * sc); o.y = f2bf(v.y * sc); o.z = f2bf(v.z * sc); o.w = f2bf(v.w * sc);
  *(ushort4*)(dst + e) = o;
}

// ---------------- generic 128x128 MFMA GEMM: C[M,N] = A[M,K] * B[N,K]^T
// EPI 0: store bf16 (proj).  EPI 1: store f32 + residual (output proj).
template<int EPI>
__global__ __launch_bounds__(256) void k_gemm(const unsigned short* __restrict__ A,
                                              const unsigned short* __restrict__ B,
                                              int M, int N, int K, int ldc,
                                              unsigned short* __restrict__ Cb,
                                              float* __restrict__ Cf,
                                              const float* __restrict__ resid){
  __shared__ __align__(16) unsigned short As[128 * 40];
  __shared__ __align__(16) unsigned short Bs[128 * 40];
  int m0 = blockIdx.y * 128, n0 = blockIdx.x * 128;
  int tid = threadIdx.x;
  int wid = tid >> 6, lane = tid & 63;
  int quad = lane >> 4, l16 = lane & 15;
  int wm = (wid >> 1) * 64, wn = (wid & 1) * 64;
  f32x4 acc[4][4];
#pragma unroll
  for (int i = 0; i < 4; i++)
#pragma unroll
    for (int j = 0; j < 4; j++) acc[i][j] = f32x4{0.f, 0.f, 0.f, 0.f};

  for (int k0 = 0; k0 < K; k0 += 32){
    __syncthreads();
#pragma unroll
    for (int c = tid; c < 512; c += 256){
      int row = c >> 2, off = (c & 3) * 8;
      *(uint4*)(&As[row * 40 + off]) = *(const uint4*)(&A[(size_t)(m0 + row) * K + k0 + off]);
      *(uint4*)(&Bs[row * 40 + off]) = *(const uint4*)(&B[(size_t)(n0 + row) * K + k0 + off]);
    }
    __syncthreads();
    bf16x8 af[4], bfr[4];
#pragma unroll
    for (int t = 0; t < 4; t++){
      af[t]  = *(const bf16x8*)(&As[(wm + t * 16 + l16) * 40 + quad * 8]);
      bfr[t] = *(const bf16x8*)(&Bs[(wn + t * 16 + l16) * 40 + quad * 8]);
    }
#pragma unroll
    for (int mt = 0; mt < 4; mt++)
#pragma unroll
      for (int nt = 0; nt < 4; nt++)
        acc[mt][nt] = __builtin_amdgcn_mfma_f32_16x16x32_bf16(af[mt], bfr[nt], acc[mt][nt], 0, 0, 0);
  }
#pragma unroll
  for (int mt = 0; mt < 4; mt++)
#pragma unroll
    for (int nt = 0; nt < 4; nt++)
#pragma unroll
      for (int r = 0; r < 4; r++){
        int row = m0 + wm + mt * 16 + quad * 4 + r;
        int col = n0 + wn + nt * 16 + l16;
        float v = acc[mt][nt][r];
        if (EPI == 0){
          Cb[(size_t)row * ldc + col] = f2bf(v);
        } else {
          Cf[(size_t)row * ldc + col] = v + resid[(size_t)row * ldc + col];
        }
      }
}

// ---------------- transpose the three V projections: vT[z][c][s]
__global__ void k_transpose_v(const unsigned short* __restrict__ proj, unsigned short* __restrict__ vT){
  __shared__ unsigned short T[64][65];
  int z = blockIdx.z;
  int s0 = blockIdx.x * 64, c0 = blockIdx.y * 64;
  int colbase = 1280 + z * 1920 + c0;   // v:1280  v_e:3200  v_o:5120
  unsigned short* dst = vT + (size_t)z * CDIM * S_LEN;
  int tid = threadIdx.x;
  for (int i = tid; i < 64 * 64; i += 256){
    int r = i >> 6, c = i & 63;
    T[r][c] = proj[(size_t)(s0 + r) * NPROJ + colbase + c];
  }
  __syncthreads();
  for (int i = tid; i < 64 * 64; i += 256){
    int c = i >> 6, r = i & 63;
    dst[(size_t)(c0 + c) * S_LEN + s0 + r] = T[r][c];
  }
}

// ---------------- flash attention, 8 heads, d=80 (DPAD=96), label mask
// FIRST: write out, else accumulate (+=). OUTSIDE: also require key im==0.
template<bool OUTSIDE, bool FIRST>
__global__ __launch_bounds__(256) void k_attn80(const unsigned short* __restrict__ proj,
                                                const unsigned short* __restrict__ vT,
                                                const int* __restrict__ labels,
                                                int qcol, int kcol,
                                                float* __restrict__ outAcc){
  __shared__ __align__(16) unsigned short Qs[64 * 104];
  __shared__ __align__(16) unsigned short Ks[64 * 104];
  __shared__ __align__(16) unsigned short Ps[64 * 72];
  __shared__ __align__(16) unsigned short Vt[80 * 72];
  __shared__ int labk[64];
  int tid = threadIdx.x, wid = tid >> 6, lane = tid & 63;
  int quad = lane >> 4, l16 = lane & 15;
  int q0 = blockIdx.x * 64;
  int h  = blockIdx.y;
  int qc = qcol + h * 80, kc = kcol + h * 80;

  // zero the d-padding cols [80,96) once (stays zero)
  for (int i = tid; i < 128; i += 256){
    int row = i >> 1, off = 80 + (i & 1) * 8;
    *(uint4*)&Qs[row * 104 + off] = make_uint4(0, 0, 0, 0);
    *(uint4*)&Ks[row * 104 + off] = make_uint4(0, 0, 0, 0);
  }
  // stage Q tile (64 x 80)
  for (int c = tid; c < 640; c += 256){
    int row = c / 10, off = (c % 10) * 8;
    *(uint4*)&Qs[row * 104 + off] = *(const uint4*)&proj[(size_t)(q0 + row) * NPROJ + qc + off];
  }
  int lq[4];
#pragma unroll
  for (int r = 0; r < 4; r++) lq[r] = labels[q0 + wid * 16 + quad * 4 + r] & 0xff;
  float mrow[4], lrow[4];
#pragma unroll
  for (int r = 0; r < 4; r++){ mrow[r] = -1e30f; lrow[r] = 0.f; }
  f32x4 Oa[5];
#pragma unroll
  for (int t = 0; t < 5; t++) Oa[t] = f32x4{0.f, 0.f, 0.f, 0.f};
  __syncthreads();
  bf16x8 qf[3];
#pragma unroll
  for (int dc = 0; dc < 3; dc++)
    qf[dc] = *(const bf16x8*)&Qs[(wid * 16 + l16) * 104 + dc * 32 + quad * 8];

  for (int kt = 0; kt < 64; kt++){
    int key0 = kt * 64;
    __syncthreads();                       // prior PV reads of Vt/Ps done
    for (int c = tid; c < 640; c += 256){
      int row = c / 10, off = (c % 10) * 8;
      *(uint4*)&Ks[row * 104 + off] = *(const uint4*)&proj[(size_t)(key0 + row) * NPROJ + kc + off];
    }
    for (int c = tid; c < 640; c += 256){
      int row = c >> 3, off = (c & 7) * 8;
      *(uint4*)&Vt[row * 72 + off] = *(const uint4*)&vT[(size_t)(h * 80 + row) * S_LEN + key0 + off];
    }
    if (tid < 64) labk[tid] = labels[key0 + tid];
    __syncthreads();

    // S = Q K^T  (scale pre-folded into Wq)
    f32x4 sa[4];
#pragma unroll
    for (int nt = 0; nt < 4; nt++){
      f32x4 a = f32x4{0.f, 0.f, 0.f, 0.f};
#pragma unroll
      for (int dc = 0; dc < 3; dc++){
        bf16x8 kf = *(const bf16x8*)&Ks[(nt * 16 + l16) * 104 + dc * 32 + quad * 8];
        a = __builtin_amdgcn_mfma_f32_16x16x32_bf16(qf[dc], kf, a, 0, 0, 0);
      }
      sa[nt] = a;
    }
    // mask + online softmax (row = quad*4+r, col = nt*16+l16)
    int lk[4];
#pragma unroll
    for (int nt = 0; nt < 4; nt++) lk[nt] = labk[nt * 16 + l16];
    float alpha[4];
#pragma unroll
    for (int r = 0; r < 4; r++){
      float mx = -1e30f;
#pragma unroll
      for (int nt = 0; nt < 4; nt++){
        bool valid = ((lk[nt] & 0xff) == lq[r]) && (!OUTSIDE || (lk[nt] & 0x100));
        float s = valid ? sa[nt][r] : -1e30f;
        sa[nt][r] = s;
        mx = fmaxf(mx, s);
      }
#pragma unroll
      for (int m = 1; m < 16; m <<= 1) mx = fmaxf(mx, __shfl_xor(mx, m));
      float mnew = fmaxf(mrow[r], mx);
      alpha[r] = __expf(mrow[r] - mnew);
      mrow[r] = mnew;
      float ps = 0.f;
#pragma unroll
      for (int nt = 0; nt < 4; nt++){
        float p = __expf(sa[nt][r] - mnew);
        sa[nt][r] = p;
        ps += p;
      }
#pragma unroll
      for (int m = 1; m < 16; m <<= 1) ps += __shfl_xor(ps, m);
      lrow[r] = lrow[r] * alpha[r] + ps;
    }
#pragma unroll
    for (int t = 0; t < 5; t++)
#pragma unroll
      for (int r = 0; r < 4; r++) Oa[t][r] *= alpha[r];
#pragma unroll
    for (int nt = 0; nt < 4; nt++)
#pragma unroll
      for (int r = 0; r < 4; r++)
        Ps[(wid * 16 + quad * 4 + r) * 72 + nt * 16 + l16] = f2bf(sa[nt][r]);
    __syncthreads();
    // O += P V
    bf16x8 pf[2];
#pragma unroll
    for (int kc2 = 0; kc2 < 2; kc2++)
      pf[kc2] = *(const bf16x8*)&Ps[(wid * 16 + l16) * 72 + kc2 * 32 + quad * 8];
#pragma unroll
    for (int kc2 = 0; kc2 < 2; kc2++)
#pragma unroll
      for (int nt = 0; nt < 5; nt++){
        bf16x8 vf = *(const bf16x8*)&Vt[(nt * 16 + l16) * 72 + kc2 * 32 + quad * 8];
        Oa[nt] = __builtin_amdgcn_mfma_f32_16x16x32_bf16(pf[kc2], vf, Oa[nt], 0, 0, 0);
      }
  }
#pragma unroll
  for (int nt = 0; nt < 5; nt++)
#pragma unroll
    for (int r = 0; r < 4; r++){
      int row = q0 + wid * 16 + quad * 4 + r;
      int col = h * 80 + nt * 16 + l16;
      float v = Oa[nt][r] / lrow[r];
      if (FIRST) outAcc[(size_t)row * CDIM + col] = v;
      else       outAcc[(size_t)row * CDIM + col] += v;
    }
}

// ---------------- entity attention: 1 head, d=640, split-K over key ranges
__global__ __launch_bounds__(256, 2) void k_attn_ent(const unsigned short* __restrict__ proj,
                                                     const unsigned short* __restrict__ veT,
                                                     const int* __restrict__ labels,
                                                     float* __restrict__ Opart,
                                                     float2* __restrict__ stats){
  __shared__ __align__(16) unsigned short Qc[64 * 40];
  __shared__ __align__(16) unsigned short Kc[64 * 40];
  __shared__ __align__(16) unsigned short Ps[64 * 72];
  __shared__ __align__(16) unsigned short Vt[64 * 72];
  __shared__ int labk[64];
  int tid = threadIdx.x, wid = tid >> 6, lane = tid & 63;
  int quad = lane >> 4, l16 = lane & 15;
  int q0 = blockIdx.x * 64;
  int split = blockIdx.y;
  int lq[4];
#pragma unroll
  for (int r = 0; r < 4; r++) lq[r] = labels[q0 + wid * 16 + quad * 4 + r] & 0xff;
  float mrow[4], lrow[4];
#pragma unroll
  for (int r = 0; r < 4; r++){ mrow[r] = -1e30f; lrow[r] = 0.f; }
  f32x4 Oa[40];
#pragma unroll
  for (int t = 0; t < 40; t++) Oa[t] = f32x4{0.f, 0.f, 0.f, 0.f};

  for (int kt = 0; kt < 16; kt++){
    int key0 = split * 1024 + kt * 64;
    if (tid < 64) labk[tid] = labels[key0 + tid];
    f32x4 sa[4];
#pragma unroll
    for (int nt = 0; nt < 4; nt++) sa[nt] = f32x4{0.f, 0.f, 0.f, 0.f};
    for (int dc = 0; dc < 20; dc++){
      __syncthreads();
      {
        int row = tid >> 2, off = (tid & 3) * 8;
        *(uint4*)&Qc[row * 40 + off] = *(const uint4*)&proj[(size_t)(q0 + row) * NPROJ + 1920 + dc * 32 + off];
        *(uint4*)&Kc[row * 40 + off] = *(const uint4*)&proj[(size_t)(key0 + row) * NPROJ + 2560 + dc * 32 + off];
      }
      __syncthreads();
      bf16x8 qf = *(const bf16x8*)&Qc[(wid * 16 + l16) * 40 + quad * 8];
#pragma unroll
      for (int nt = 0; nt < 4; nt++){
        bf16x8 kf = *(const bf16x8*)&Kc[(nt * 16 + l16) * 40 + quad * 8];
        sa[nt] = __builtin_amdgcn_mfma_f32_16x16x32_bf16(qf, kf, sa[nt], 0, 0, 0);
      }
    }
    int lk[4];
#pragma unroll
    for (int nt = 0; nt < 4; nt++) lk[nt] = labk[nt * 16 + l16];
    float alpha[4];
#pragma unroll
    for (int r = 0; r < 4; r++){
      float mx = -1e30f;
#pragma unroll
      for (int nt = 0; nt < 4; nt++){
        bool valid = ((lk[nt] & 0xff) == lq[r]);
        float s = valid ? sa[nt][r] : -1e30f;
        sa[nt][r] = s;
        mx = fmaxf(mx, s);
      }
#pragma unroll
      for (int m = 1; m < 16; m <<= 1) mx = fmaxf(mx, __shfl_xor(mx, m));
      float mnew = fmaxf(mrow[r], mx);
      alpha[r] = __expf(mrow[r] - mnew);
      mrow[r] = mnew;
      float ps = 0.f;
#pragma unroll
      for (int nt = 0; nt < 4; nt++){
        float p = __expf(sa[nt][r] - mnew);
        sa[nt][r] = p;
        ps += p;
      }
#pragma unroll
      for (int m = 1; m < 16; m <<= 1) ps += __shfl_xor(ps, m);
      lrow[r] = lrow[r] * alpha[r] + ps;
    }
#pragma unroll
    for (int t = 0; t < 40; t++)
#pragma unroll
      for (int r = 0; r < 4; r++) Oa[t][r] *= alpha[r];
#pragma unroll
    for (int nt = 0; nt < 4; nt++)
#pragma unroll
      for (int r = 0; r < 4; r++)
        Ps[(wid * 16 + quad * 4 + r) * 72 + nt * 16 + l16] = f2bf(sa[nt][r]);
    __syncthreads();
    bf16x8 pf[2];
#pragma unroll
    for (int kc2 = 0; kc2 < 2; kc2++)
      pf[kc2] = *(const bf16x8*)&Ps[(wid * 16 + l16) * 72 + kc2 * 32 + quad * 8];
    for (int nc = 0; nc < 10; nc++){
      __syncthreads();
#pragma unroll
      for (int c = tid; c < 512; c += 256){
        int row = c >> 3, off = (c & 7) * 8;
        *(uint4*)&Vt[row * 72 + off] = *(const uint4*)&veT[(size_t)(nc * 64 + row) * S_LEN + key0 + off];
      }
      __syncthreads();
#pragma unroll
      for (int kc2 = 0; kc2 < 2; kc2++)
#pragma unroll
        for (int nt = 0; nt < 4; nt++){
          bf16x8 vf = *(const bf16x8*)&Vt[(nt * 16 + l16) * 72 + kc2 * 32 + quad * 8];
          Oa[nc * 4 + nt] = __builtin_amdgcn_mfma_f32_16x16x32_bf16(pf[kc2], vf, Oa[nc * 4 + nt], 0, 0, 0);
        }
    }
  }
#pragma unroll
  for (int t = 0; t < 40; t++)
#pragma unroll
    for (int r = 0; r < 4; r++){
      int row = q0 + wid * 16 + quad * 4 + r;
      Opart[((size_t)split * S_LEN + row) * CDIM + t * 16 + l16] = Oa[t][r];
    }
  if (l16 == 0){
#pragma unroll
    for (int r = 0; r < 4; r++){
      int row = q0 + wid * 16 + quad * 4 + r;
      stats[(size_t)split * S_LEN + row] = make_float2(mrow[r], lrow[r]);
    }
  }
}

// ---------------- combine: attnAcc + entity(split-K merge), cast to bf16
__global__ void k_combine(const float* __restrict__ attnAcc, const float* __restrict__ Opart,
                          const float2* __restrict__ stats, unsigned short* __restrict__ attnS){
  int s = blockIdx.x;
  float2 st[4];
  float M = -1e30f;
#pragma unroll
  for (int p = 0; p < 4; p++){ st[p] = stats[(size_t)p * S_LEN + s]; M = fmaxf(M, st[p].x); }
  float w[4], L = 0.f;
#pragma unroll
  for (int p = 0; p < 4; p++){ w[p] = __expf(st[p].x - M); L += w[p] * st[p].y; }
  float invL = 1.f / L;
  for (int c = threadIdx.x; c < CDIM; c += 256){
    float e = 0.f;
#pragma unroll
    for (int p = 0; p < 4; p++) e += w[p] * Opart[((size_t)p * S_LEN + s) * CDIM + c];
    float v = attnAcc[(size_t)s * CDIM + c] + e * invL;
    attnS[(size_t)s * CDIM + c] = f2bf(v);
  }
}

extern "C" void kernel_launch(void* const* d_in, const int* in_sizes, int n_in,
                              void* d_out, int out_size, void* d_ws, size_t ws_size,
                              hipStream_t stream){
  const float* hs  = (const float*)d_in[0];
  const int* mask  = (const int*)d_in[1];
  const int* inp   = (const int*)d_in[2];
  char* ws = (char*)d_ws;
  int*            labels  = (int*)(ws + 0);
  unsigned short* hsb     = (unsigned short*)(ws + 16384);
  unsigned short* Wall    = (unsigned short*)(ws + 5259264);
  unsigned short* proj    = (unsigned short*)(ws + 13451264);
  unsigned short* vT      = (unsigned short*)(ws + 60637184);
  float*          attnAcc = (float*)(ws + 76365824);
  float*          Opart   = (float*)(ws + 86851584);
  float2*         stats   = (float2*)(ws + 128794624);
  unsigned short* attnS   = (unsigned short*)(ws + 128925696);
  unsigned short* Wob     = Wall + 9 * 409600;

  k_labels<<<16, 256, 0, stream>>>(mask, inp, labels);
  k_cvt_hs<<<(S_LEN * CDIM / 4 + 255) / 256, 256, 0, stream>>>(hs, hsb, S_LEN * CDIM);
  WPtrs wp;
  for (int i = 0; i < 10; i++) wp.w[i] = (const float*)d_in[3 + i];
  k_cvt_w<<<(10 * 409600 / 4 + 255) / 256, 256, 0, stream>>>(wp, Wall);

  // all 9 projections in one GEMM: [4096 x 640] x [5760 x 640]^T
  k_gemm<0><<<dim3(45, 32), 256, 0, stream>>>(hsb, Wall, S_LEN, NPROJ, CDIM, NPROJ,
                                              proj, nullptr, nullptr);
  k_transpose_v<<<dim3(64, 10, 3), 256, 0, stream>>>(proj, vT);

  // branch 1: q,k,v (cols 0,640,1280), 8 heads, same-entity mask
  k_attn80<false, true><<<dim3(64, 8), 256, 0, stream>>>(proj, vT, labels, 0, 640, attnAcc);
  // branch 3: q_o,k_o,v_o (cols 3840,4480,5120), same-entity AND outside key
  k_attn80<true, false><<<dim3(64, 8), 256, 0, stream>>>(proj, vT + (size_t)2 * CDIM * S_LEN,
                                                         labels, 3840, 4480, attnAcc);
  // branch 2: entity, 1 head d=640, split-K=4
  k_attn_ent<<<dim3(64, 4), 256, 0, stream>>>(proj, vT + (size_t)1 * CDIM * S_LEN,
                                              labels, Opart, stats);
  k_combine<<<S_LEN, 256, 0, stream>>>(attnAcc, Opart, stats, attnS);

  // out = attnS @ Wo^T + residual
  k_gemm<1><<<dim3(5, 32), 256, 0, stream>>>(attnS, Wob, S_LEN, CDIM, CDIM, CDIM,
                                             nullptr, (float*)d_out, hs);
}

// Round 2
// 994.325 us; speedup vs baseline: 1.0301x; 1.0301x over previous
//
#include <hip/hip_runtime.h>
#include <cstdint>

typedef __attribute__((ext_vector_type(8))) short bf16x8;
typedef __attribute__((ext_vector_type(4))) float f32x4;

#define S_LEN 4096
#define CDIM  640
#define NPROJ 5760

__device__ __forceinline__ unsigned short f2bf(float f){
  union { float f; uint32_t u; } v; v.f = f;
  uint32_t u = v.u;
  return (unsigned short)((u + 0x7fffu + ((u >> 16) & 1u)) >> 16);
}

// ---------------- labels: nearest-resize 512x512 -> 64x64, pack m | (im==0)<<8
__global__ void k_labels(const int* __restrict__ mask, const int* __restrict__ inp,
                         int* __restrict__ labels){
  int s = blockIdx.x * 256 + threadIdx.x;
  if (s >= S_LEN) return;
  int y = s >> 6, x = s & 63;
  int off = (y * 8) * 512 + x * 8;   // floor(i*512/64) = i*8
  int m = mask[off] & 0xff;
  int o = (inp[off] == 0) ? 0x100 : 0;
  labels[s] = m | o;
}

// ---------------- f32 -> bf16 converts
__global__ void k_cvt_hs(const float* __restrict__ src, unsigned short* __restrict__ dst, int n){
  int idx = (blockIdx.x * 256 + threadIdx.x) * 4;
  if (idx >= n) return;
  float4 v = *(const float4*)(src + idx);
  ushort4 o;
  o.x = f2bf(v.x); o.y = f2bf(v.y); o.z = f2bf(v.z); o.w = f2bf(v.w);
  *(ushort4*)(dst + idx) = o;
}

struct WPtrs { const float* w[10]; };

__global__ void k_cvt_w(WPtrs p, unsigned short* __restrict__ dst){
  int e = (blockIdx.x * 256 + threadIdx.x) * 4;
  if (e >= 10 * 409600) return;
  int a = e / 409600, r = e % 409600;
  // fold softmax 1/sqrt(d) into Q-projection weights
  float sc = (a == 0 || a == 6) ? 0.11180339887498948f   // 1/sqrt(80)
           : (a == 3 ? 0.03952847075210474f : 1.0f);     // 1/sqrt(640)
  float4 v = *(const float4*)(p.w[a] + r);
  ushort4 o;
  o.x = f2bf(v.x * sc); o.y = f2bf(v.y * sc); o.z = f2bf(v.z * sc); o.w = f2bf(v.w * sc);
  *(ushort4*)(dst + e) = o;
}

// ---------------- generic 128x128 MFMA GEMM: C[M,N] = A[M,K] * B[N,K]^T
template<int EPI>
__global__ __launch_bounds__(256) void k_gemm(const unsigned short* __restrict__ A,
                                              const unsigned short* __restrict__ B,
                                              int M, int N, int K, int ldc,
                                              unsigned short* __restrict__ Cb,
                                              float* __restrict__ Cf,
                                              const float* __restrict__ resid){
  __shared__ __align__(16) unsigned short As[128 * 40];
  __shared__ __align__(16) unsigned short Bs[128 * 40];
  int m0 = blockIdx.y * 128, n0 = blockIdx.x * 128;
  int tid = threadIdx.x;
  int wid = tid >> 6, lane = tid & 63;
  int quad = lane >> 4, l16 = lane & 15;
  int wm = (wid >> 1) * 64, wn = (wid & 1) * 64;
  f32x4 acc[4][4];
#pragma unroll
  for (int i = 0; i < 4; i++)
#pragma unroll
    for (int j = 0; j < 4; j++) acc[i][j] = f32x4{0.f, 0.f, 0.f, 0.f};

  for (int k0 = 0; k0 < K; k0 += 32){
    __syncthreads();
#pragma unroll
    for (int c = tid; c < 512; c += 256){
      int row = c >> 2, off = (c & 3) * 8;
      *(uint4*)(&As[row * 40 + off]) = *(const uint4*)(&A[(size_t)(m0 + row) * K + k0 + off]);
      *(uint4*)(&Bs[row * 40 + off]) = *(const uint4*)(&B[(size_t)(n0 + row) * K + k0 + off]);
    }
    __syncthreads();
    bf16x8 af[4], bfr[4];
#pragma unroll
    for (int t = 0; t < 4; t++){
      af[t]  = *(const bf16x8*)(&As[(wm + t * 16 + l16) * 40 + quad * 8]);
      bfr[t] = *(const bf16x8*)(&Bs[(wn + t * 16 + l16) * 40 + quad * 8]);
    }
#pragma unroll
    for (int mt = 0; mt < 4; mt++)
#pragma unroll
      for (int nt = 0; nt < 4; nt++)
        acc[mt][nt] = __builtin_amdgcn_mfma_f32_16x16x32_bf16(af[mt], bfr[nt], acc[mt][nt], 0, 0, 0);
  }
#pragma unroll
  for (int mt = 0; mt < 4; mt++)
#pragma unroll
    for (int nt = 0; nt < 4; nt++)
#pragma unroll
      for (int r = 0; r < 4; r++){
        int row = m0 + wm + mt * 16 + quad * 4 + r;
        int col = n0 + wn + nt * 16 + l16;
        float v = acc[mt][nt][r];
        if (EPI == 0){
          Cb[(size_t)row * ldc + col] = f2bf(v);
        } else {
          Cf[(size_t)row * ldc + col] = v + resid[(size_t)row * ldc + col];
        }
      }
}

// ---------------- transpose the three V projections: vT[z][c][s]
__global__ void k_transpose_v(const unsigned short* __restrict__ proj, unsigned short* __restrict__ vT){
  __shared__ unsigned short T[64][65];
  int z = blockIdx.z;
  int s0 = blockIdx.x * 64, c0 = blockIdx.y * 64;
  int colbase = 1280 + z * 1920 + c0;   // v:1280  v_e:3200  v_o:5120
  unsigned short* dst = vT + (size_t)z * CDIM * S_LEN;
  int tid = threadIdx.x;
  for (int i = tid; i < 64 * 64; i += 256){
    int r = i >> 6, c = i & 63;
    T[r][c] = proj[(size_t)(s0 + r) * NPROJ + colbase + c];
  }
  __syncthreads();
  for (int i = tid; i < 64 * 64; i += 256){
    int c = i >> 6, r = i & 63;
    dst[(size_t)(c0 + c) * S_LEN + s0 + r] = T[r][c];
  }
}

// ---------------- flash attention, 8 heads, d=80 (DPAD=96/104 pitch), label mask
// v2: register prefetch of next K/V tile overlaps global latency with compute.
template<bool OUTSIDE, bool FIRST>
__global__ __launch_bounds__(256) void k_attn80(const unsigned short* __restrict__ proj,
                                                const unsigned short* __restrict__ vT,
                                                const int* __restrict__ labels,
                                                int qcol, int kcol,
                                                float* __restrict__ outAcc){
  __shared__ __align__(16) unsigned short Qs[64 * 104];
  __shared__ __align__(16) unsigned short Ks[64 * 104];
  __shared__ __align__(16) unsigned short Ps[64 * 72];
  __shared__ __align__(16) unsigned short Vt[80 * 72];
  __shared__ int labk[64];
  int tid = threadIdx.x, wid = tid >> 6, lane = tid & 63;
  int quad = lane >> 4, l16 = lane & 15;
  int q0 = blockIdx.x * 64;
  int h  = blockIdx.y;
  int qc = qcol + h * 80, kc = kcol + h * 80;

  // zero the d-padding cols [80,96) once (stays zero)
  for (int i = tid; i < 128; i += 256){
    int row = i >> 1, off = 80 + (i & 1) * 8;
    *(uint4*)&Qs[row * 104 + off] = make_uint4(0, 0, 0, 0);
    *(uint4*)&Ks[row * 104 + off] = make_uint4(0, 0, 0, 0);
  }
  // stage Q tile (64 x 80)
  for (int c = tid; c < 640; c += 256){
    int row = c / 10, off = (c % 10) * 8;
    *(uint4*)&Qs[row * 104 + off] = *(const uint4*)&proj[(size_t)(q0 + row) * NPROJ + qc + off];
  }
  int lq[4];
#pragma unroll
  for (int r = 0; r < 4; r++) lq[r] = labels[q0 + wid * 16 + quad * 4 + r] & 0xff;
  float mrow[4], lrow[4];
#pragma unroll
  for (int r = 0; r < 4; r++){ mrow[r] = -1e30f; lrow[r] = 0.f; }
  f32x4 Oa[5];
#pragma unroll
  for (int t = 0; t < 5; t++) Oa[t] = f32x4{0.f, 0.f, 0.f, 0.f};
  __syncthreads();
  bf16x8 qf[3];
#pragma unroll
  for (int dc = 0; dc < 3; dc++)
    qf[dc] = *(const bf16x8*)&Qs[(wid * 16 + l16) * 104 + dc * 32 + quad * 8];

  // register prefetch state
  uint4 kpre[3], vpre[3];
  int labpre = 0;
  int kr[3], ko[3], vr[3], vo[3];
#pragma unroll
  for (int u = 0; u < 3; u++){
    int c = tid + u * 256;
    kr[u] = c / 10; ko[u] = (c % 10) * 8;
    vr[u] = c >> 3; vo[u] = (c & 7) * 8;
  }
  // prefetch tile 0
#pragma unroll
  for (int u = 0; u < 3; u++){
    int c = tid + u * 256;
    if (c < 640){
      kpre[u] = *(const uint4*)&proj[(size_t)(0 + kr[u]) * NPROJ + kc + ko[u]];
      vpre[u] = *(const uint4*)&vT[(size_t)(h * 80 + vr[u]) * S_LEN + 0 + vo[u]];
    }
  }
  if (tid < 64) labpre = labels[tid];

  for (int kt = 0; kt < 64; kt++){
    __syncthreads();                       // prior tile's LDS reads done
    // commit prefetched tile to LDS
#pragma unroll
    for (int u = 0; u < 3; u++){
      int c = tid + u * 256;
      if (c < 640){
        *(uint4*)&Ks[kr[u] * 104 + ko[u]] = kpre[u];
        *(uint4*)&Vt[vr[u] * 72 + vo[u]] = vpre[u];
      }
    }
    if (tid < 64) labk[tid] = labpre;
    __syncthreads();
    // issue prefetch for next tile (overlaps with compute below)
    {
      int knext = (kt == 63) ? 0 : (kt + 1) * 64;
#pragma unroll
      for (int u = 0; u < 3; u++){
        int c = tid + u * 256;
        if (c < 640){
          kpre[u] = *(const uint4*)&proj[(size_t)(knext + kr[u]) * NPROJ + kc + ko[u]];
          vpre[u] = *(const uint4*)&vT[(size_t)(h * 80 + vr[u]) * S_LEN + knext + vo[u]];
        }
      }
      if (tid < 64) labpre = labels[knext + tid];
    }

    // S = Q K^T  (scale pre-folded into Wq)
    f32x4 sa[4];
#pragma unroll
    for (int nt = 0; nt < 4; nt++){
      f32x4 a = f32x4{0.f, 0.f, 0.f, 0.f};
#pragma unroll
      for (int dc = 0; dc < 3; dc++){
        bf16x8 kf = *(const bf16x8*)&Ks[(nt * 16 + l16) * 104 + dc * 32 + quad * 8];
        a = __builtin_amdgcn_mfma_f32_16x16x32_bf16(qf[dc], kf, a, 0, 0, 0);
      }
      sa[nt] = a;
    }
    // mask + online softmax (row = quad*4+r, col = nt*16+l16)
    int lk[4];
#pragma unroll
    for (int nt = 0; nt < 4; nt++) lk[nt] = labk[nt * 16 + l16];
    float alpha[4];
#pragma unroll
    for (int r = 0; r < 4; r++){
      float mx = -1e30f;
#pragma unroll
      for (int nt = 0; nt < 4; nt++){
        bool valid = ((lk[nt] & 0xff) == lq[r]) && (!OUTSIDE || (lk[nt] & 0x100));
        float s = valid ? sa[nt][r] : -1e30f;
        sa[nt][r] = s;
        mx = fmaxf(mx, s);
      }
#pragma unroll
      for (int m = 1; m < 16; m <<= 1) mx = fmaxf(mx, __shfl_xor(mx, m));
      float mnew = fmaxf(mrow[r], mx);
      alpha[r] = __expf(mrow[r] - mnew);
      mrow[r] = mnew;
      float ps = 0.f;
#pragma unroll
      for (int nt = 0; nt < 4; nt++){
        float p = __expf(sa[nt][r] - mnew);
        sa[nt][r] = p;
        ps += p;
      }
#pragma unroll
      for (int m = 1; m < 16; m <<= 1) ps += __shfl_xor(ps, m);
      lrow[r] = lrow[r] * alpha[r] + ps;
    }
#pragma unroll
    for (int t = 0; t < 5; t++)
#pragma unroll
      for (int r = 0; r < 4; r++) Oa[t][r] *= alpha[r];
#pragma unroll
    for (int nt = 0; nt < 4; nt++)
#pragma unroll
      for (int r = 0; r < 4; r++)
        Ps[(wid * 16 + quad * 4 + r) * 72 + nt * 16 + l16] = f2bf(sa[nt][r]);
    __syncthreads();
    // O += P V
    bf16x8 pf[2];
#pragma unroll
    for (int kc2 = 0; kc2 < 2; kc2++)
      pf[kc2] = *(const bf16x8*)&Ps[(wid * 16 + l16) * 72 + kc2 * 32 + quad * 8];
#pragma unroll
    for (int kc2 = 0; kc2 < 2; kc2++)
#pragma unroll
      for (int nt = 0; nt < 5; nt++){
        bf16x8 vf = *(const bf16x8*)&Vt[(nt * 16 + l16) * 72 + kc2 * 32 + quad * 8];
        Oa[nt] = __builtin_amdgcn_mfma_f32_16x16x32_bf16(pf[kc2], vf, Oa[nt], 0, 0, 0);
      }
  }
#pragma unroll
  for (int nt = 0; nt < 5; nt++)
#pragma unroll
    for (int r = 0; r < 4; r++){
      int row = q0 + wid * 16 + quad * 4 + r;
      int col = h * 80 + nt * 16 + l16;
      float v = Oa[nt][r] / lrow[r];
      if (FIRST) outAcc[(size_t)row * CDIM + col] = v;
      else       outAcc[(size_t)row * CDIM + col] += v;
    }
}

// ---------------- entity attention v2: 1 head, d=640, split-K=4
// Q fragments in registers; K staged in 2x(64x320) chunks; V^T in 2x(320x64).
// 8 barriers / 160 MFMA per wave per 64-key tile (was ~62 barriers).
__global__ __launch_bounds__(256, 1) void k_attn_ent(const unsigned short* __restrict__ proj,
                                                     const unsigned short* __restrict__ veT,
                                                     const int* __restrict__ labels,
                                                     float* __restrict__ Opart,
                                                     float2* __restrict__ stats){
  __shared__ __align__(16) unsigned short Buf[320 * 72];   // union: K[64][328] / V[320][72]
  __shared__ __align__(16) unsigned short Ps[64 * 72];
  __shared__ int labk[64];
  int tid = threadIdx.x, wid = tid >> 6, lane = tid & 63;
  int quad = lane >> 4, l16 = lane & 15;
  int q0 = blockIdx.x * 64;
  int split = blockIdx.y;
  int qrow = q0 + wid * 16 + l16;

  // Q fragments resident in registers (A-operand layout: row=l16-of-wave-tile, k=quad*8+j)
  bf16x8 qf[20];
#pragma unroll
  for (int dc = 0; dc < 20; dc++)
    qf[dc] = *(const bf16x8*)&proj[(size_t)qrow * NPROJ + 1920 + dc * 32 + quad * 8];

  int lq[4];
#pragma unroll
  for (int r = 0; r < 4; r++) lq[r] = labels[q0 + wid * 16 + quad * 4 + r] & 0xff;
  float mrow[4], lrow[4];
#pragma unroll
  for (int r = 0; r < 4; r++){ mrow[r] = -1e30f; lrow[r] = 0.f; }
  f32x4 Oa[40];
#pragma unroll
  for (int t = 0; t < 40; t++) Oa[t] = f32x4{0.f, 0.f, 0.f, 0.f};

  for (int kt = 0; kt < 16; kt++){
    int key0 = split * 1024 + kt * 64;
    f32x4 sa[4];
#pragma unroll
    for (int nt = 0; nt < 4; nt++) sa[nt] = f32x4{0.f, 0.f, 0.f, 0.f};

    // ---- QK^T over two 320-col K chunks
#pragma unroll
    for (int ch = 0; ch < 2; ch++){
      __syncthreads();                       // Buf free (prev phase's reads done)
      if (ch == 0 && tid < 64) labk[tid] = labels[key0 + tid];
      for (int i = tid; i < 2560; i += 256){
        int row = i / 40, j = i % 40;
        *(uint4*)&Buf[row * 328 + j * 8] =
          *(const uint4*)&proj[(size_t)(key0 + row) * NPROJ + 2560 + ch * 320 + j * 8];
      }
      __syncthreads();
#pragma unroll
      for (int dc = 0; dc < 10; dc++)
#pragma unroll
        for (int nt = 0; nt < 4; nt++){
          bf16x8 kf = *(const bf16x8*)&Buf[(nt * 16 + l16) * 328 + dc * 32 + quad * 8];
          sa[nt] = __builtin_amdgcn_mfma_f32_16x16x32_bf16(qf[ch * 10 + dc], kf, sa[nt], 0, 0, 0);
        }
    }

    // ---- mask + online softmax
    int lk[4];
#pragma unroll
    for (int nt = 0; nt < 4; nt++) lk[nt] = labk[nt * 16 + l16];
    float alpha[4];
#pragma unroll
    for (int r = 0; r < 4; r++){
      float mx = -1e30f;
#pragma unroll
      for (int nt = 0; nt < 4; nt++){
        bool valid = ((lk[nt] & 0xff) == lq[r]);
        float s = valid ? sa[nt][r] : -1e30f;
        sa[nt][r] = s;
        mx = fmaxf(mx, s);
      }
#pragma unroll
      for (int m = 1; m < 16; m <<= 1) mx = fmaxf(mx, __shfl_xor(mx, m));
      float mnew = fmaxf(mrow[r], mx);
      alpha[r] = __expf(mrow[r] - mnew);
      mrow[r] = mnew;
      float ps = 0.f;
#pragma unroll
      for (int nt = 0; nt < 4; nt++){
        float p = __expf(sa[nt][r] - mnew);
        sa[nt][r] = p;
        ps += p;
      }
#pragma unroll
      for (int m = 1; m < 16; m <<= 1) ps += __shfl_xor(ps, m);
      lrow[r] = lrow[r] * alpha[r] + ps;
    }
#pragma unroll
    for (int t = 0; t < 40; t++)
#pragma unroll
      for (int r = 0; r < 4; r++) Oa[t][r] *= alpha[r];
#pragma unroll
    for (int nt = 0; nt < 4; nt++)
#pragma unroll
      for (int r = 0; r < 4; r++)
        Ps[(wid * 16 + quad * 4 + r) * 72 + nt * 16 + l16] = f2bf(sa[nt][r]);

    // ---- O += P V over two 320-row V^T chunks
#pragma unroll
    for (int ch = 0; ch < 2; ch++){
      __syncthreads();                       // Buf free; (ch==0) also publishes Ps
      for (int i = tid; i < 2560; i += 256){
        int row = i >> 3, j = i & 7;
        *(uint4*)&Buf[row * 72 + j * 8] =
          *(const uint4*)&veT[(size_t)(ch * 320 + row) * S_LEN + key0 + j * 8];
      }
      __syncthreads();
      bf16x8 pf[2];
#pragma unroll
      for (int kc2 = 0; kc2 < 2; kc2++)
        pf[kc2] = *(const bf16x8*)&Ps[(wid * 16 + l16) * 72 + kc2 * 32 + quad * 8];
#pragma unroll
      for (int kc2 = 0; kc2 < 2; kc2++)
#pragma unroll
        for (int nt = 0; nt < 20; nt++){
          bf16x8 vf = *(const bf16x8*)&Buf[(nt * 16 + l16) * 72 + kc2 * 32 + quad * 8];
          Oa[ch * 20 + nt] = __builtin_amdgcn_mfma_f32_16x16x32_bf16(pf[kc2], vf, Oa[ch * 20 + nt], 0, 0, 0);
        }
    }
  }

#pragma unroll
  for (int t = 0; t < 40; t++)
#pragma unroll
    for (int r = 0; r < 4; r++){
      int row = q0 + wid * 16 + quad * 4 + r;
      Opart[((size_t)split * S_LEN + row) * CDIM + t * 16 + l16] = Oa[t][r];
    }
  if (l16 == 0){
#pragma unroll
    for (int r = 0; r < 4; r++){
      int row = q0 + wid * 16 + quad * 4 + r;
      stats[(size_t)split * S_LEN + row] = make_float2(mrow[r], lrow[r]);
    }
  }
}

// ---------------- combine: attnAcc + entity(split-K merge), cast to bf16
__global__ void k_combine(const float* __restrict__ attnAcc, const float* __restrict__ Opart,
                          const float2* __restrict__ stats, unsigned short* __restrict__ attnS){
  int s = blockIdx.x;
  float2 st[4];
  float M = -1e30f;
#pragma unroll
  for (int p = 0; p < 4; p++){ st[p] = stats[(size_t)p * S_LEN + s]; M = fmaxf(M, st[p].x); }
  float w[4], L = 0.f;
#pragma unroll
  for (int p = 0; p < 4; p++){ w[p] = __expf(st[p].x - M); L += w[p] * st[p].y; }
  float invL = 1.f / L;
  for (int c = threadIdx.x; c < CDIM; c += 256){
    float e = 0.f;
#pragma unroll
    for (int p = 0; p < 4; p++) e += w[p] * Opart[((size_t)p * S_LEN + s) * CDIM + c];
    float v = attnAcc[(size_t)s * CDIM + c] + e * invL;
    attnS[(size_t)s * CDIM + c] = f2bf(v);
  }
}

extern "C" void kernel_launch(void* const* d_in, const int* in_sizes, int n_in,
                              void* d_out, int out_size, void* d_ws, size_t ws_size,
                              hipStream_t stream){
  const float* hs  = (const float*)d_in[0];
  const int* mask  = (const int*)d_in[1];
  const int* inp   = (const int*)d_in[2];
  char* ws = (char*)d_ws;
  int*            labels  = (int*)(ws + 0);
  unsigned short* hsb     = (unsigned short*)(ws + 16384);
  unsigned short* Wall    = (unsigned short*)(ws + 5259264);
  unsigned short* proj    = (unsigned short*)(ws + 13451264);
  unsigned short* vT      = (unsigned short*)(ws + 60637184);
  float*          attnAcc = (float*)(ws + 76365824);
  float*          Opart   = (float*)(ws + 86851584);
  float2*         stats   = (float2*)(ws + 128794624);
  unsigned short* attnS   = (unsigned short*)(ws + 128925696);
  unsigned short* Wob     = Wall + 9 * 409600;

  k_labels<<<16, 256, 0, stream>>>(mask, inp, labels);
  k_cvt_hs<<<(S_LEN * CDIM / 4 + 255) / 256, 256, 0, stream>>>(hs, hsb, S_LEN * CDIM);
  WPtrs wp;
  for (int i = 0; i < 10; i++) wp.w[i] = (const float*)d_in[3 + i];
  k_cvt_w<<<(10 * 409600 / 4 + 255) / 256, 256, 0, stream>>>(wp, Wall);

  // all 9 projections in one GEMM: [4096 x 640] x [5760 x 640]^T
  k_gemm<0><<<dim3(45, 32), 256, 0, stream>>>(hsb, Wall, S_LEN, NPROJ, CDIM, NPROJ,
                                              proj, nullptr, nullptr);
  k_transpose_v<<<dim3(64, 10, 3), 256, 0, stream>>>(proj, vT);

  // branch 1: q,k,v (cols 0,640,1280), 8 heads, same-entity mask
  k_attn80<false, true><<<dim3(64, 8), 256, 0, stream>>>(proj, vT, labels, 0, 640, attnAcc);
  // branch 3: q_o,k_o,v_o (cols 3840,4480,5120), same-entity AND outside key
  k_attn80<true, false><<<dim3(64, 8), 256, 0, stream>>>(proj, vT + (size_t)2 * CDIM * S_LEN,
                                                         labels, 3840, 4480, attnAcc);
  // branch 2: entity, 1 head d=640, split-K=4
  k_attn_ent<<<dim3(64, 4), 256, 0, stream>>>(proj, vT + (size_t)1 * CDIM * S_LEN,
                                              labels, Opart, stats);
  k_combine<<<S_LEN, 256, 0, stream>>>(attnAcc, Opart, stats, attnS);

  // out = attnS @ Wo^T + residual
  k_gemm<1><<<dim3(5, 32), 256, 0, stream>>>(attnS, Wob, S_LEN, CDIM, CDIM, CDIM,
                                             nullptr, (float*)d_out, hs);
}

// Round 3
// 671.071 us; speedup vs baseline: 1.5263x; 1.4817x over previous
//
#include <hip/hip_runtime.h>
#include <cstdint>

typedef __attribute__((ext_vector_type(8))) short bf16x8;
typedef __attribute__((ext_vector_type(4))) float f32x4;

#define S_LEN 4096
#define CDIM  640
#define NPROJ 5760

__device__ __forceinline__ unsigned short f2bf(float f){
  union { float f; uint32_t u; } v; v.f = f;
  uint32_t u = v.u;
  return (unsigned short)((u + 0x7fffu + ((u >> 16) & 1u)) >> 16);
}

// ---------------- labels: nearest-resize 512x512 -> 64x64, pack m | (im==0)<<8
__global__ void k_labels(const int* __restrict__ mask, const int* __restrict__ inp,
                         int* __restrict__ labels){
  int s = blockIdx.x * 256 + threadIdx.x;
  if (s >= S_LEN) return;
  int y = s >> 6, x = s & 63;
  int off = (y * 8) * 512 + x * 8;   // floor(i*512/64) = i*8
  int m = mask[off] & 0xff;
  int o = (inp[off] == 0) ? 0x100 : 0;
  labels[s] = m | o;
}

// ---------------- bucket sort by label value (4 buckets)
__global__ void k_hist(const int* __restrict__ labels, int* __restrict__ boff, int* __restrict__ cnt){
  __shared__ int h[4];
  if (threadIdx.x < 4) h[threadIdx.x] = 0;
  __syncthreads();
  for (int s = threadIdx.x; s < S_LEN; s += 256) atomicAdd(&h[labels[s] & 3], 1);
  __syncthreads();
  if (threadIdx.x == 0){
    int a = 0;
    for (int c = 0; c < 4; c++){ boff[c] = a; a += h[c]; }
    boff[4] = a;
  }
  if (threadIdx.x < 4) cnt[threadIdx.x] = 0;
}

__global__ void k_perm(const int* __restrict__ labels, const int* __restrict__ boff,
                       int* __restrict__ cnt, int* __restrict__ perm,
                       int* __restrict__ inv, int* __restrict__ labP){
  int s = blockIdx.x * 256 + threadIdx.x;
  if (s >= S_LEN) return;
  int lab = labels[s];
  int c = lab & 3;
  int pos = boff[c] + atomicAdd(&cnt[c], 1);
  perm[pos] = s; inv[s] = pos; labP[pos] = lab;
}

// per 64-query-tile key range (covers all buckets the tile's rows intersect)
__global__ void k_tiles(const int* __restrict__ labP, const int* __restrict__ boff,
                        int2* __restrict__ tr){
  int t = threadIdx.x;
  if (t >= 64) return;
  int c0 = labP[t * 64] & 3, c1 = labP[t * 64 + 63] & 3;
  int lo = boff[c0] & ~63;
  int hi = (boff[c1 + 1] + 63) & ~63;
  tr[t] = make_int2(lo, hi);
}

// ---------------- f32 -> bf16 converts
__global__ void k_cvt_hs(const float* __restrict__ src, unsigned short* __restrict__ dst, int n){
  int idx = (blockIdx.x * 256 + threadIdx.x) * 4;
  if (idx >= n) return;
  float4 v = *(const float4*)(src + idx);
  ushort4 o;
  o.x = f2bf(v.x); o.y = f2bf(v.y); o.z = f2bf(v.z); o.w = f2bf(v.w);
  *(ushort4*)(dst + idx) = o;
}

struct WPtrs { const float* w[10]; };

__global__ void k_cvt_w(WPtrs p, unsigned short* __restrict__ dst){
  int e = (blockIdx.x * 256 + threadIdx.x) * 4;
  if (e >= 10 * 409600) return;
  int a = e / 409600, r = e % 409600;
  float sc = (a == 0 || a == 6) ? 0.11180339887498948f   // 1/sqrt(80)
           : (a == 3 ? 0.03952847075210474f : 1.0f);     // 1/sqrt(640)
  float4 v = *(const float4*)(p.w[a] + r);
  ushort4 o;
  o.x = f2bf(v.x * sc); o.y = f2bf(v.y * sc); o.z = f2bf(v.z * sc); o.w = f2bf(v.w * sc);
  *(ushort4*)(dst + e) = o;
}

// ---------------- 128x128 MFMA GEMM: C[M,N] = A[M,K] * B[N,K]^T
// EPI 0: store bf16 with C-rows scattered through rowmap (inv). 
// EPI 1: store f32 + residual, rows scattered through rowmap (perm).
template<int EPI>
__global__ __launch_bounds__(256) void k_gemm(const unsigned short* __restrict__ A,
                                              const unsigned short* __restrict__ B,
                                              int M, int N, int K, int ldc,
                                              const int* __restrict__ rowmap,
                                              unsigned short* __restrict__ Cb,
                                              float* __restrict__ Cf,
                                              const float* __restrict__ resid){
  __shared__ __align__(16) unsigned short As[128 * 40];
  __shared__ __align__(16) unsigned short Bs[128 * 40];
  int m0 = blockIdx.y * 128, n0 = blockIdx.x * 128;
  int tid = threadIdx.x;
  int wid = tid >> 6, lane = tid & 63;
  int quad = lane >> 4, l16 = lane & 15;
  int wm = (wid >> 1) * 64, wn = (wid & 1) * 64;
  f32x4 acc[4][4];
#pragma unroll
  for (int i = 0; i < 4; i++)
#pragma unroll
    for (int j = 0; j < 4; j++) acc[i][j] = f32x4{0.f, 0.f, 0.f, 0.f};

  for (int k0 = 0; k0 < K; k0 += 32){
    __syncthreads();
#pragma unroll
    for (int c = tid; c < 512; c += 256){
      int row = c >> 2, off = (c & 3) * 8;
      *(uint4*)(&As[row * 40 + off]) = *(const uint4*)(&A[(size_t)(m0 + row) * K + k0 + off]);
      *(uint4*)(&Bs[row * 40 + off]) = *(const uint4*)(&B[(size_t)(n0 + row) * K + k0 + off]);
    }
    __syncthreads();
    bf16x8 af[4], bfr[4];
#pragma unroll
    for (int t = 0; t < 4; t++){
      af[t]  = *(const bf16x8*)(&As[(wm + t * 16 + l16) * 40 + quad * 8]);
      bfr[t] = *(const bf16x8*)(&Bs[(wn + t * 16 + l16) * 40 + quad * 8]);
    }
#pragma unroll
    for (int mt = 0; mt < 4; mt++)
#pragma unroll
      for (int nt = 0; nt < 4; nt++)
        acc[mt][nt] = __builtin_amdgcn_mfma_f32_16x16x32_bf16(af[mt], bfr[nt], acc[mt][nt], 0, 0, 0);
  }
#pragma unroll
  for (int mt = 0; mt < 4; mt++)
#pragma unroll
    for (int nt = 0; nt < 4; nt++)
#pragma unroll
      for (int r = 0; r < 4; r++){
        int row = m0 + wm + mt * 16 + quad * 4 + r;
        int col = n0 + wn + nt * 16 + l16;
        float v = acc[mt][nt][r];
        if (EPI == 0){
          Cb[(size_t)rowmap[row] * ldc + col] = f2bf(v);
        } else {
          int ro = rowmap[row];
          Cf[(size_t)ro * ldc + col] = v + resid[(size_t)ro * ldc + col];
        }
      }
}

// ---------------- transpose the three V projections: vT[z][c][s] (permuted key index)
__global__ void k_transpose_v(const unsigned short* __restrict__ proj, unsigned short* __restrict__ vT){
  __shared__ unsigned short T[64][65];
  int z = blockIdx.z;
  int s0 = blockIdx.x * 64, c0 = blockIdx.y * 64;
  int colbase = 1280 + z * 1920 + c0;   // v:1280  v_e:3200  v_o:5120
  unsigned short* dst = vT + (size_t)z * CDIM * S_LEN;
  int tid = threadIdx.x;
  for (int i = tid; i < 64 * 64; i += 256){
    int r = i >> 6, c = i & 63;
    T[r][c] = proj[(size_t)(s0 + r) * NPROJ + colbase + c];
  }
  __syncthreads();
  for (int i = tid; i < 64 * 64; i += 256){
    int c = i >> 6, r = i & 63;
    dst[(size_t)(c0 + c) * S_LEN + s0 + r] = T[r][c];
  }
}

// ---------------- flash attention, 8 heads, d=80, bucketed key range, label mask
template<bool OUTSIDE, bool FIRST>
__global__ __launch_bounds__(256) void k_attn80(const unsigned short* __restrict__ proj,
                                                const unsigned short* __restrict__ vT,
                                                const int* __restrict__ labP,
                                                const int2* __restrict__ tileRange,
                                                int qcol, int kcol,
                                                float* __restrict__ outAcc){
  __shared__ __align__(16) unsigned short Qs[64 * 104];
  __shared__ __align__(16) unsigned short Ks[64 * 104];
  __shared__ __align__(16) unsigned short Ps[64 * 72];
  __shared__ __align__(16) unsigned short Vt[80 * 72];
  __shared__ int labk[64];
  int tid = threadIdx.x, wid = tid >> 6, lane = tid & 63;
  int quad = lane >> 4, l16 = lane & 15;
  int q0 = blockIdx.x * 64;
  int h  = blockIdx.y;
  int qc = qcol + h * 80, kc = kcol + h * 80;
  int2 range = tileRange[blockIdx.x];
  int t0 = range.x >> 6, t1 = range.y >> 6;

  for (int i = tid; i < 128; i += 256){
    int row = i >> 1, off = 80 + (i & 1) * 8;
    *(uint4*)&Qs[row * 104 + off] = make_uint4(0, 0, 0, 0);
    *(uint4*)&Ks[row * 104 + off] = make_uint4(0, 0, 0, 0);
  }
  for (int c = tid; c < 640; c += 256){
    int row = c / 10, off = (c % 10) * 8;
    *(uint4*)&Qs[row * 104 + off] = *(const uint4*)&proj[(size_t)(q0 + row) * NPROJ + qc + off];
  }
  int lq[4];
#pragma unroll
  for (int r = 0; r < 4; r++) lq[r] = labP[q0 + wid * 16 + quad * 4 + r] & 0xff;
  float mrow[4], lrow[4];
#pragma unroll
  for (int r = 0; r < 4; r++){ mrow[r] = -1e30f; lrow[r] = 0.f; }
  f32x4 Oa[5];
#pragma unroll
  for (int t = 0; t < 5; t++) Oa[t] = f32x4{0.f, 0.f, 0.f, 0.f};
  __syncthreads();
  bf16x8 qf[3];
#pragma unroll
  for (int dc = 0; dc < 3; dc++)
    qf[dc] = *(const bf16x8*)&Qs[(wid * 16 + l16) * 104 + dc * 32 + quad * 8];

  // register prefetch state
  uint4 kpre[3], vpre[3];
  int labpre = 0;
  int kr[3], ko[3], vr[3], vo[3];
#pragma unroll
  for (int u = 0; u < 3; u++){
    int c = tid + u * 256;
    kr[u] = c / 10; ko[u] = (c % 10) * 8;
    vr[u] = c >> 3; vo[u] = (c & 7) * 8;
  }
#pragma unroll
  for (int u = 0; u < 3; u++){
    int c = tid + u * 256;
    if (c < 640){
      kpre[u] = *(const uint4*)&proj[(size_t)(t0 * 64 + kr[u]) * NPROJ + kc + ko[u]];
      vpre[u] = *(const uint4*)&vT[(size_t)(h * 80 + vr[u]) * S_LEN + t0 * 64 + vo[u]];
    }
  }
  if (tid < 64) labpre = labP[t0 * 64 + tid];

  for (int kt = t0; kt < t1; kt++){
    __syncthreads();
#pragma unroll
    for (int u = 0; u < 3; u++){
      int c = tid + u * 256;
      if (c < 640){
        *(uint4*)&Ks[kr[u] * 104 + ko[u]] = kpre[u];
        *(uint4*)&Vt[vr[u] * 72 + vo[u]] = vpre[u];
      }
    }
    if (tid < 64) labk[tid] = labpre;
    __syncthreads();
    {
      int knext = (kt + 1 < t1) ? (kt + 1) * 64 : t0 * 64;
#pragma unroll
      for (int u = 0; u < 3; u++){
        int c = tid + u * 256;
        if (c < 640){
          kpre[u] = *(const uint4*)&proj[(size_t)(knext + kr[u]) * NPROJ + kc + ko[u]];
          vpre[u] = *(const uint4*)&vT[(size_t)(h * 80 + vr[u]) * S_LEN + knext + vo[u]];
        }
      }
      if (tid < 64) labpre = labP[knext + tid];
    }

    f32x4 sa[4];
#pragma unroll
    for (int nt = 0; nt < 4; nt++){
      f32x4 a = f32x4{0.f, 0.f, 0.f, 0.f};
#pragma unroll
      for (int dc = 0; dc < 3; dc++){
        bf16x8 kf = *(const bf16x8*)&Ks[(nt * 16 + l16) * 104 + dc * 32 + quad * 8];
        a = __builtin_amdgcn_mfma_f32_16x16x32_bf16(qf[dc], kf, a, 0, 0, 0);
      }
      sa[nt] = a;
    }
    int lk[4];
#pragma unroll
    for (int nt = 0; nt < 4; nt++) lk[nt] = labk[nt * 16 + l16];
    float alpha[4];
#pragma unroll
    for (int r = 0; r < 4; r++){
      float mx = -1e30f;
#pragma unroll
      for (int nt = 0; nt < 4; nt++){
        bool valid = ((lk[nt] & 0xff) == lq[r]) && (!OUTSIDE || (lk[nt] & 0x100));
        float s = valid ? sa[nt][r] : -1e30f;
        sa[nt][r] = s;
        mx = fmaxf(mx, s);
      }
#pragma unroll
      for (int m = 1; m < 16; m <<= 1) mx = fmaxf(mx, __shfl_xor(mx, m));
      float mnew = fmaxf(mrow[r], mx);
      alpha[r] = __expf(mrow[r] - mnew);
      mrow[r] = mnew;
      float ps = 0.f;
#pragma unroll
      for (int nt = 0; nt < 4; nt++){
        float p = __expf(sa[nt][r] - mnew);
        sa[nt][r] = p;
        ps += p;
      }
#pragma unroll
      for (int m = 1; m < 16; m <<= 1) ps += __shfl_xor(ps, m);
      lrow[r] = lrow[r] * alpha[r] + ps;
    }
#pragma unroll
    for (int t = 0; t < 5; t++)
#pragma unroll
      for (int r = 0; r < 4; r++) Oa[t][r] *= alpha[r];
#pragma unroll
    for (int nt = 0; nt < 4; nt++)
#pragma unroll
      for (int r = 0; r < 4; r++)
        Ps[(wid * 16 + quad * 4 + r) * 72 + nt * 16 + l16] = f2bf(sa[nt][r]);
    __syncthreads();
    bf16x8 pf[2];
#pragma unroll
    for (int kc2 = 0; kc2 < 2; kc2++)
      pf[kc2] = *(const bf16x8*)&Ps[(wid * 16 + l16) * 72 + kc2 * 32 + quad * 8];
#pragma unroll
    for (int kc2 = 0; kc2 < 2; kc2++)
#pragma unroll
      for (int nt = 0; nt < 5; nt++){
        bf16x8 vf = *(const bf16x8*)&Vt[(nt * 16 + l16) * 72 + kc2 * 32 + quad * 8];
        Oa[nt] = __builtin_amdgcn_mfma_f32_16x16x32_bf16(pf[kc2], vf, Oa[nt], 0, 0, 0);
      }
  }
#pragma unroll
  for (int nt = 0; nt < 5; nt++)
#pragma unroll
    for (int r = 0; r < 4; r++){
      int row = q0 + wid * 16 + quad * 4 + r;
      int col = h * 80 + nt * 16 + l16;
      float v = Oa[nt][r] / lrow[r];
      if (FIRST) outAcc[(size_t)row * CDIM + col] = v;
      else       outAcc[(size_t)row * CDIM + col] += v;
    }
}

// ---------------- entity attention: 1 head, d=640, bucketed keys, split-K=4
__global__ __launch_bounds__(256, 1) void k_attn_ent(const unsigned short* __restrict__ proj,
                                                     const unsigned short* __restrict__ veT,
                                                     const int* __restrict__ labP,
                                                     const int2* __restrict__ tileRange,
                                                     float* __restrict__ Opart,
                                                     float2* __restrict__ stats){
  __shared__ __align__(16) unsigned short Buf[320 * 72];   // union: K[64][328] / V[320][72]
  __shared__ __align__(16) unsigned short Ps[64 * 72];
  __shared__ int labk[64];
  int tid = threadIdx.x, wid = tid >> 6, lane = tid & 63;
  int quad = lane >> 4, l16 = lane & 15;
  int q0 = blockIdx.x * 64;
  int split = blockIdx.y;
  int qrow = q0 + wid * 16 + l16;
  int2 range = tileRange[blockIdx.x];
  int t0 = range.x >> 6, t1 = range.y >> 6;
  int nkt = t1 - t0;
  int ta = t0 + (nkt * split) / 4, tb = t0 + (nkt * (split + 1)) / 4;

  bf16x8 qf[20];
#pragma unroll
  for (int dc = 0; dc < 20; dc++)
    qf[dc] = *(const bf16x8*)&proj[(size_t)qrow * NPROJ + 1920 + dc * 32 + quad * 8];

  int lq[4];
#pragma unroll
  for (int r = 0; r < 4; r++) lq[r] = labP[q0 + wid * 16 + quad * 4 + r] & 0xff;
  float mrow[4], lrow[4];
#pragma unroll
  for (int r = 0; r < 4; r++){ mrow[r] = -1e30f; lrow[r] = 0.f; }
  f32x4 Oa[40];
#pragma unroll
  for (int t = 0; t < 40; t++) Oa[t] = f32x4{0.f, 0.f, 0.f, 0.f};

  for (int kt = ta; kt < tb; kt++){
    int key0 = kt * 64;
    f32x4 sa[4];
#pragma unroll
    for (int nt = 0; nt < 4; nt++) sa[nt] = f32x4{0.f, 0.f, 0.f, 0.f};

#pragma unroll
    for (int ch = 0; ch < 2; ch++){
      __syncthreads();
      if (ch == 0 && tid < 64) labk[tid] = labP[key0 + tid];
      for (int i = tid; i < 2560; i += 256){
        int row = i / 40, j = i % 40;
        *(uint4*)&Buf[row * 328 + j * 8] =
          *(const uint4*)&proj[(size_t)(key0 + row) * NPROJ + 2560 + ch * 320 + j * 8];
      }
      __syncthreads();
#pragma unroll
      for (int dc = 0; dc < 10; dc++)
#pragma unroll
        for (int nt = 0; nt < 4; nt++){
          bf16x8 kf = *(const bf16x8*)&Buf[(nt * 16 + l16) * 328 + dc * 32 + quad * 8];
          sa[nt] = __builtin_amdgcn_mfma_f32_16x16x32_bf16(qf[ch * 10 + dc], kf, sa[nt], 0, 0, 0);
        }
    }

    int lk[4];
#pragma unroll
    for (int nt = 0; nt < 4; nt++) lk[nt] = labk[nt * 16 + l16];
    float alpha[4];
#pragma unroll
    for (int r = 0; r < 4; r++){
      float mx = -1e30f;
#pragma unroll
      for (int nt = 0; nt < 4; nt++){
        bool valid = ((lk[nt] & 0xff) == lq[r]);
        float s = valid ? sa[nt][r] : -1e30f;
        sa[nt][r] = s;
        mx = fmaxf(mx, s);
      }
#pragma unroll
      for (int m = 1; m < 16; m <<= 1) mx = fmaxf(mx, __shfl_xor(mx, m));
      float mnew = fmaxf(mrow[r], mx);
      alpha[r] = __expf(mrow[r] - mnew);
      mrow[r] = mnew;
      float ps = 0.f;
#pragma unroll
      for (int nt = 0; nt < 4; nt++){
        float p = __expf(sa[nt][r] - mnew);
        sa[nt][r] = p;
        ps += p;
      }
#pragma unroll
      for (int m = 1; m < 16; m <<= 1) ps += __shfl_xor(ps, m);
      lrow[r] = lrow[r] * alpha[r] + ps;
    }
#pragma unroll
    for (int t = 0; t < 40; t++)
#pragma unroll
      for (int r = 0; r < 4; r++) Oa[t][r] *= alpha[r];
#pragma unroll
    for (int nt = 0; nt < 4; nt++)
#pragma unroll
      for (int r = 0; r < 4; r++)
        Ps[(wid * 16 + quad * 4 + r) * 72 + nt * 16 + l16] = f2bf(sa[nt][r]);

#pragma unroll
    for (int ch = 0; ch < 2; ch++){
      __syncthreads();
      for (int i = tid; i < 2560; i += 256){
        int row = i >> 3, j = i & 7;
        *(uint4*)&Buf[row * 72 + j * 8] =
          *(const uint4*)&veT[(size_t)(ch * 320 + row) * S_LEN + key0 + j * 8];
      }
      __syncthreads();
      bf16x8 pf[2];
#pragma unroll
      for (int kc2 = 0; kc2 < 2; kc2++)
        pf[kc2] = *(const bf16x8*)&Ps[(wid * 16 + l16) * 72 + kc2 * 32 + quad * 8];
#pragma unroll
      for (int kc2 = 0; kc2 < 2; kc2++)
#pragma unroll
        for (int nt = 0; nt < 20; nt++){
          bf16x8 vf = *(const bf16x8*)&Buf[(nt * 16 + l16) * 72 + kc2 * 32 + quad * 8];
          Oa[ch * 20 + nt] = __builtin_amdgcn_mfma_f32_16x16x32_bf16(pf[kc2], vf, Oa[ch * 20 + nt], 0, 0, 0);
        }
    }
  }

#pragma unroll
  for (int t = 0; t < 40; t++)
#pragma unroll
    for (int r = 0; r < 4; r++){
      int row = q0 + wid * 16 + quad * 4 + r;
      Opart[((size_t)split * S_LEN + row) * CDIM + t * 16 + l16] = Oa[t][r];
    }
  if (l16 == 0){
#pragma unroll
    for (int r = 0; r < 4; r++){
      int row = q0 + wid * 16 + quad * 4 + r;
      stats[(size_t)split * S_LEN + row] = make_float2(mrow[r], lrow[r]);
    }
  }
}

// ---------------- combine (permuted space): attnAcc + entity split-K merge -> bf16
__global__ void k_combine(const float* __restrict__ attnAcc, const float* __restrict__ Opart,
                          const float2* __restrict__ stats, unsigned short* __restrict__ attnS){
  int s = blockIdx.x;
  float2 st[4];
  float M = -1e30f;
#pragma unroll
  for (int p = 0; p < 4; p++){ st[p] = stats[(size_t)p * S_LEN + s]; M = fmaxf(M, st[p].x); }
  float w[4], L = 0.f;
#pragma unroll
  for (int p = 0; p < 4; p++){ w[p] = __expf(st[p].x - M); L += w[p] * st[p].y; }
  float invL = 1.f / L;
  for (int c = threadIdx.x; c < CDIM; c += 256){
    float e = 0.f;
#pragma unroll
    for (int p = 0; p < 4; p++) e += w[p] * Opart[((size_t)p * S_LEN + s) * CDIM + c];
    float v = attnAcc[(size_t)s * CDIM + c] + e * invL;
    attnS[(size_t)s * CDIM + c] = f2bf(v);
  }
}

extern "C" void kernel_launch(void* const* d_in, const int* in_sizes, int n_in,
                              void* d_out, int out_size, void* d_ws, size_t ws_size,
                              hipStream_t stream){
  const float* hs  = (const float*)d_in[0];
  const int* mask  = (const int*)d_in[1];
  const int* inp   = (const int*)d_in[2];
  char* ws = (char*)d_ws;
  int*            labels  = (int*)(ws + 0);
  int*            boff    = (int*)(ws + 16384);
  int*            cnt     = (int*)(ws + 16640);
  int*            perm    = (int*)(ws + 16896);
  int*            inv     = (int*)(ws + 33280);
  int*            labP    = (int*)(ws + 49664);
  int2*           tileR   = (int2*)(ws + 66048);
  unsigned short* hsb     = (unsigned short*)(ws + 131072);
  unsigned short* Wall    = (unsigned short*)(ws + 5373952);
  unsigned short* proj    = (unsigned short*)(ws + 13565952);
  unsigned short* vT      = (unsigned short*)(ws + 60751872);
  float*          attnAcc = (float*)(ws + 76480512);
  float*          Opart   = (float*)(ws + 86966272);
  float2*         stats   = (float2*)(ws + 128909312);
  unsigned short* attnS   = (unsigned short*)(ws + 129040384);
  unsigned short* Wob     = Wall + 9 * 409600;

  k_labels<<<16, 256, 0, stream>>>(mask, inp, labels);
  k_hist<<<1, 256, 0, stream>>>(labels, boff, cnt);
  k_perm<<<16, 256, 0, stream>>>(labels, boff, cnt, perm, inv, labP);
  k_tiles<<<1, 64, 0, stream>>>(labP, boff, tileR);
  k_cvt_hs<<<(S_LEN * CDIM / 4 + 255) / 256, 256, 0, stream>>>(hs, hsb, S_LEN * CDIM);
  WPtrs wp;
  for (int i = 0; i < 10; i++) wp.w[i] = (const float*)d_in[3 + i];
  k_cvt_w<<<(10 * 409600 / 4 + 255) / 256, 256, 0, stream>>>(wp, Wall);

  // all 9 projections in one GEMM, rows scattered into bucket-permuted order
  k_gemm<0><<<dim3(45, 32), 256, 0, stream>>>(hsb, Wall, S_LEN, NPROJ, CDIM, NPROJ,
                                              inv, proj, nullptr, nullptr);
  k_transpose_v<<<dim3(64, 10, 3), 256, 0, stream>>>(proj, vT);

  // branch 1: q,k,v (cols 0,640,1280), 8 heads, same-entity mask
  k_attn80<false, true><<<dim3(64, 8), 256, 0, stream>>>(proj, vT, labP, tileR, 0, 640, attnAcc);
  // branch 3: q_o,k_o,v_o (cols 3840,4480,5120), same-entity AND outside key
  k_attn80<true, false><<<dim3(64, 8), 256, 0, stream>>>(proj, vT + (size_t)2 * CDIM * S_LEN,
                                                         labP, tileR, 3840, 4480, attnAcc);
  // branch 2: entity, 1 head d=640, split-K=4
  k_attn_ent<<<dim3(64, 4), 256, 0, stream>>>(proj, vT + (size_t)1 * CDIM * S_LEN,
                                              labP, tileR, Opart, stats);
  k_combine<<<S_LEN, 256, 0, stream>>>(attnAcc, Opart, stats, attnS);

  // out = attnS @ Wo^T + residual, un-permuted via perm in the epilogue
  k_gemm<1><<<dim3(5, 32), 256, 0, stream>>>(attnS, Wob, S_LEN, CDIM, CDIM, CDIM,
                                             perm, nullptr, (float*)d_out, hs);
}

// Round 4
// 612.297 us; speedup vs baseline: 1.6728x; 1.0960x over previous
//
#include <hip/hip_runtime.h>
#include <cstdint>

typedef __attribute__((ext_vector_type(8))) short bf16x8;
typedef __attribute__((ext_vector_type(4))) float f32x4;

#define S_LEN 4096
#define CDIM  640
#define NPROJ 5760

__device__ __forceinline__ unsigned short f2bf(float f){
  union { float f; uint32_t u; } v; v.f = f;
  uint32_t u = v.u;
  return (unsigned short)((u + 0x7fffu + ((u >> 16) & 1u)) >> 16);
}

// ---------------- labels: nearest-resize 512x512 -> 64x64, pack m | (im==0)<<8
__global__ void k_labels(const int* __restrict__ mask, const int* __restrict__ inp,
                         int* __restrict__ labels){
  int s = blockIdx.x * 256 + threadIdx.x;
  if (s >= S_LEN) return;
  int y = s >> 6, x = s & 63;
  int off = (y * 8) * 512 + x * 8;
  int m = mask[off] & 0xff;
  int o = (inp[off] == 0) ? 0x100 : 0;
  labels[s] = m | o;
}

// ---------------- bucket sort by label value (4 buckets)
__global__ void k_hist(const int* __restrict__ labels, int* __restrict__ boff, int* __restrict__ cnt){
  __shared__ int h[4];
  if (threadIdx.x < 4) h[threadIdx.x] = 0;
  __syncthreads();
  for (int s = threadIdx.x; s < S_LEN; s += 256) atomicAdd(&h[labels[s] & 3], 1);
  __syncthreads();
  if (threadIdx.x == 0){
    int a = 0;
    for (int c = 0; c < 4; c++){ boff[c] = a; a += h[c]; }
    boff[4] = a;
  }
  if (threadIdx.x < 4) cnt[threadIdx.x] = 0;
}

__global__ void k_perm(const int* __restrict__ labels, const int* __restrict__ boff,
                       int* __restrict__ cnt, int* __restrict__ perm,
                       int* __restrict__ inv, int* __restrict__ labP){
  int s = blockIdx.x * 256 + threadIdx.x;
  if (s >= S_LEN) return;
  int lab = labels[s];
  int c = lab & 3;
  int pos = boff[c] + atomicAdd(&cnt[c], 1);
  perm[pos] = s; inv[s] = pos; labP[pos] = lab;
}

// per 64-tile (attn80) and per 128-tile (entity) key ranges; zero rowsum
__global__ void k_tiles(const int* __restrict__ labP, const int* __restrict__ boff,
                        int2* __restrict__ tr, int4* __restrict__ qtinfo,
                        float* __restrict__ rowsum){
  int t = threadIdx.x;
  __shared__ int nkt[32];
  if (t < 64){
    int c0 = labP[t * 64] & 3, c1 = labP[t * 64 + 63] & 3;
    tr[t] = make_int2(boff[c0] & ~63, (boff[c1 + 1] + 63) & ~63);
  }
  if (t < 32){
    int c0 = labP[t * 128] & 3, c1 = labP[t * 128 + 127] & 3;
    int lo = boff[c0] & ~127, hi = (boff[c1 + 1] + 127) & ~127;
    qtinfo[t].x = lo; qtinfo[t].y = hi; qtinfo[t].w = 0;
    nkt[t] = (hi - lo) >> 7;
  }
  __syncthreads();
  if (t == 0){
    int a = 0;
    for (int i = 0; i < 32; i++){ qtinfo[i].z = a; a += nkt[i]; }
  }
  for (int s = t; s < S_LEN; s += 256) rowsum[s] = 0.f;
}

__global__ void k_zero(float4* __restrict__ p, int n){
  int i = blockIdx.x * 256 + threadIdx.x;
  if (i < n) p[i] = float4{0.f, 0.f, 0.f, 0.f};
}

// ---------------- f32 -> bf16 converts
__global__ void k_cvt_hs(const float* __restrict__ src, unsigned short* __restrict__ dst, int n){
  int idx = (blockIdx.x * 256 + threadIdx.x) * 4;
  if (idx >= n) return;
  float4 v = *(const float4*)(src + idx);
  ushort4 o;
  o.x = f2bf(v.x); o.y = f2bf(v.y); o.z = f2bf(v.z); o.w = f2bf(v.w);
  *(ushort4*)(dst + idx) = o;
}

struct WPtrs { const float* w[10]; };

__global__ void k_cvt_w(WPtrs p, unsigned short* __restrict__ dst){
  int e = (blockIdx.x * 256 + threadIdx.x) * 4;
  if (e >= 10 * 409600) return;
  int a = e / 409600, r = e % 409600;
  float sc = (a == 0 || a == 6) ? 0.11180339887498948f   // 1/sqrt(80)
           : (a == 3 ? 0.03952847075210474f : 1.0f);     // 1/sqrt(640)
  float4 v = *(const float4*)(p.w[a] + r);
  ushort4 o;
  o.x = f2bf(v.x * sc); o.y = f2bf(v.y * sc); o.z = f2bf(v.z * sc); o.w = f2bf(v.w * sc);
  *(ushort4*)(dst + e) = o;
}

// ---------------- 128x128 MFMA GEMM: C[M,N] = A[M,K] * B[N,K]^T
template<int EPI>
__global__ __launch_bounds__(256) void k_gemm(const unsigned short* __restrict__ A,
                                              const unsigned short* __restrict__ B,
                                              int M, int N, int K, int ldc,
                                              const int* __restrict__ rowmap,
                                              unsigned short* __restrict__ Cb,
                                              float* __restrict__ Cf,
                                              const float* __restrict__ resid){
  __shared__ __align__(16) unsigned short As[128 * 40];
  __shared__ __align__(16) unsigned short Bs[128 * 40];
  int m0 = blockIdx.y * 128, n0 = blockIdx.x * 128;
  int tid = threadIdx.x;
  int wid = tid >> 6, lane = tid & 63;
  int quad = lane >> 4, l16 = lane & 15;
  int wm = (wid >> 1) * 64, wn = (wid & 1) * 64;
  f32x4 acc[4][4];
#pragma unroll
  for (int i = 0; i < 4; i++)
#pragma unroll
    for (int j = 0; j < 4; j++) acc[i][j] = f32x4{0.f, 0.f, 0.f, 0.f};

  for (int k0 = 0; k0 < K; k0 += 32){
    __syncthreads();
#pragma unroll
    for (int c = tid; c < 512; c += 256){
      int row = c >> 2, off = (c & 3) * 8;
      *(uint4*)(&As[row * 40 + off]) = *(const uint4*)(&A[(size_t)(m0 + row) * K + k0 + off]);
      *(uint4*)(&Bs[row * 40 + off]) = *(const uint4*)(&B[(size_t)(n0 + row) * K + k0 + off]);
    }
    __syncthreads();
    bf16x8 af[4], bfr[4];
#pragma unroll
    for (int t = 0; t < 4; t++){
      af[t]  = *(const bf16x8*)(&As[(wm + t * 16 + l16) * 40 + quad * 8]);
      bfr[t] = *(const bf16x8*)(&Bs[(wn + t * 16 + l16) * 40 + quad * 8]);
    }
#pragma unroll
    for (int mt = 0; mt < 4; mt++)
#pragma unroll
      for (int nt = 0; nt < 4; nt++)
        acc[mt][nt] = __builtin_amdgcn_mfma_f32_16x16x32_bf16(af[mt], bfr[nt], acc[mt][nt], 0, 0, 0);
  }
#pragma unroll
  for (int mt = 0; mt < 4; mt++)
#pragma unroll
    for (int nt = 0; nt < 4; nt++)
#pragma unroll
      for (int r = 0; r < 4; r++){
        int row = m0 + wm + mt * 16 + quad * 4 + r;
        int col = n0 + wn + nt * 16 + l16;
        float v = acc[mt][nt][r];
        if (EPI == 0){
          Cb[(size_t)rowmap[row] * ldc + col] = f2bf(v);
        } else {
          int ro = rowmap[row];
          Cf[(size_t)ro * ldc + col] = v + resid[(size_t)ro * ldc + col];
        }
      }
}

// ---------------- transpose the three V projections: vT[z][c][s] (permuted key index)
__global__ void k_transpose_v(const unsigned short* __restrict__ proj, unsigned short* __restrict__ vT){
  __shared__ unsigned short T[64][65];
  int z = blockIdx.z;
  int s0 = blockIdx.x * 64, c0 = blockIdx.y * 64;
  int colbase = 1280 + z * 1920 + c0;   // v:1280  v_e:3200  v_o:5120
  unsigned short* dst = vT + (size_t)z * CDIM * S_LEN;
  int tid = threadIdx.x;
  for (int i = tid; i < 64 * 64; i += 256){
    int r = i >> 6, c = i & 63;
    T[r][c] = proj[(size_t)(s0 + r) * NPROJ + colbase + c];
  }
  __syncthreads();
  for (int i = tid; i < 64 * 64; i += 256){
    int c = i >> 6, r = i & 63;
    dst[(size_t)(c0 + c) * S_LEN + s0 + r] = T[r][c];
  }
}

// ---------------- flash attention, both d=80 branches (z=0: orig, z=1: outside)
__global__ __launch_bounds__(256) void k_attn80(const unsigned short* __restrict__ proj,
                                                const unsigned short* __restrict__ vT,
                                                const int* __restrict__ labP,
                                                const int2* __restrict__ tileRange,
                                                float* __restrict__ outAcc){
  __shared__ __align__(16) unsigned short Ks[64 * 104];
  __shared__ __align__(16) unsigned short Ps[64 * 72];
  __shared__ __align__(16) unsigned short Vt[80 * 72];
  __shared__ int labk[64];
  int tid = threadIdx.x, wid = tid >> 6, lane = tid & 63;
  int quad = lane >> 4, l16 = lane & 15;
  int q0 = blockIdx.x * 64;
  int h  = blockIdx.y;
  bool OUTSIDE = (blockIdx.z == 1);
  int qc = (OUTSIDE ? 3840 : 0) + h * 80;
  int kc = (OUTSIDE ? 4480 : 640) + h * 80;
  const unsigned short* vTb = vT + (size_t)(OUTSIDE ? 2 : 0) * CDIM * S_LEN;
  int2 range = tileRange[blockIdx.x];
  int t0 = range.x >> 6, t1 = range.y >> 6;

  // zero the K d-padding cols [80,96) once (stays zero)
  for (int i = tid; i < 128; i += 256){
    int row = i >> 1, off = 80 + (i & 1) * 8;
    *(uint4*)&Ks[row * 104 + off] = make_uint4(0, 0, 0, 0);
  }
  // Q fragments straight from global (A-layout: row=l16, k=quad*8+j)
  int qrow = q0 + wid * 16 + l16;
  bf16x8 qf[3];
  qf[0] = *(const bf16x8*)&proj[(size_t)qrow * NPROJ + qc + quad * 8];
  qf[1] = *(const bf16x8*)&proj[(size_t)qrow * NPROJ + qc + 32 + quad * 8];
  if (quad < 2) qf[2] = *(const bf16x8*)&proj[(size_t)qrow * NPROJ + qc + 64 + quad * 8];
  else          qf[2] = bf16x8{0, 0, 0, 0, 0, 0, 0, 0};

  int lq[4];
#pragma unroll
  for (int r = 0; r < 4; r++) lq[r] = labP[q0 + wid * 16 + quad * 4 + r] & 0xff;
  float mrow[4], lrow[4];
#pragma unroll
  for (int r = 0; r < 4; r++){ mrow[r] = -1e30f; lrow[r] = 0.f; }
  f32x4 Oa[5];
#pragma unroll
  for (int t = 0; t < 5; t++) Oa[t] = f32x4{0.f, 0.f, 0.f, 0.f};

  // register prefetch state
  uint4 kpre[3], vpre[3];
  int labpre = 0;
  int kr[3], ko[3], vr[3], vo[3];
#pragma unroll
  for (int u = 0; u < 3; u++){
    int c = tid + u * 256;
    kr[u] = c / 10; ko[u] = (c % 10) * 8;
    vr[u] = c >> 3; vo[u] = (c & 7) * 8;
  }
#pragma unroll
  for (int u = 0; u < 3; u++){
    int c = tid + u * 256;
    if (c < 640){
      kpre[u] = *(const uint4*)&proj[(size_t)(t0 * 64 + kr[u]) * NPROJ + kc + ko[u]];
      vpre[u] = *(const uint4*)&vTb[(size_t)(h * 80 + vr[u]) * S_LEN + t0 * 64 + vo[u]];
    }
  }
  if (tid < 64) labpre = labP[t0 * 64 + tid];

  for (int kt = t0; kt < t1; kt++){
    __syncthreads();
#pragma unroll
    for (int u = 0; u < 3; u++){
      int c = tid + u * 256;
      if (c < 640){
        *(uint4*)&Ks[kr[u] * 104 + ko[u]] = kpre[u];
        *(uint4*)&Vt[vr[u] * 72 + vo[u]] = vpre[u];
      }
    }
    if (tid < 64) labk[tid] = labpre;
    __syncthreads();
    {
      int knext = (kt + 1 < t1) ? (kt + 1) * 64 : t0 * 64;
#pragma unroll
      for (int u = 0; u < 3; u++){
        int c = tid + u * 256;
        if (c < 640){
          kpre[u] = *(const uint4*)&proj[(size_t)(knext + kr[u]) * NPROJ + kc + ko[u]];
          vpre[u] = *(const uint4*)&vTb[(size_t)(h * 80 + vr[u]) * S_LEN + knext + vo[u]];
        }
      }
      if (tid < 64) labpre = labP[knext + tid];
    }

    f32x4 sa[4];
#pragma unroll
    for (int nt = 0; nt < 4; nt++){
      f32x4 a = f32x4{0.f, 0.f, 0.f, 0.f};
#pragma unroll
      for (int dc = 0; dc < 3; dc++){
        bf16x8 kf = *(const bf16x8*)&Ks[(nt * 16 + l16) * 104 + dc * 32 + quad * 8];
        a = __builtin_amdgcn_mfma_f32_16x16x32_bf16(qf[dc], kf, a, 0, 0, 0);
      }
      sa[nt] = a;
    }
    int lk[4];
#pragma unroll
    for (int nt = 0; nt < 4; nt++) lk[nt] = labk[nt * 16 + l16];
    float alpha[4];
#pragma unroll
    for (int r = 0; r < 4; r++){
      float mx = -1e30f;
#pragma unroll
      for (int nt = 0; nt < 4; nt++){
        bool valid = ((lk[nt] & 0xff) == lq[r]) && (!OUTSIDE || (lk[nt] & 0x100));
        float s = valid ? sa[nt][r] : -1e30f;
        sa[nt][r] = s;
        mx = fmaxf(mx, s);
      }
#pragma unroll
      for (int m = 1; m < 16; m <<= 1) mx = fmaxf(mx, __shfl_xor(mx, m));
      float mnew = fmaxf(mrow[r], mx);
      alpha[r] = __expf(mrow[r] - mnew);
      mrow[r] = mnew;
      float ps = 0.f;
#pragma unroll
      for (int nt = 0; nt < 4; nt++){
        float p = __expf(sa[nt][r] - mnew);
        sa[nt][r] = p;
        ps += p;
      }
#pragma unroll
      for (int m = 1; m < 16; m <<= 1) ps += __shfl_xor(ps, m);
      lrow[r] = lrow[r] * alpha[r] + ps;
    }
#pragma unroll
    for (int t = 0; t < 5; t++)
#pragma unroll
      for (int r = 0; r < 4; r++) Oa[t][r] *= alpha[r];
#pragma unroll
    for (int nt = 0; nt < 4; nt++)
#pragma unroll
      for (int r = 0; r < 4; r++)
        Ps[(wid * 16 + quad * 4 + r) * 72 + nt * 16 + l16] = f2bf(sa[nt][r]);
    __syncthreads();
    bf16x8 pf[2];
#pragma unroll
    for (int kc2 = 0; kc2 < 2; kc2++)
      pf[kc2] = *(const bf16x8*)&Ps[(wid * 16 + l16) * 72 + kc2 * 32 + quad * 8];
#pragma unroll
    for (int kc2 = 0; kc2 < 2; kc2++)
#pragma unroll
      for (int nt = 0; nt < 5; nt++){
        bf16x8 vf = *(const bf16x8*)&Vt[(nt * 16 + l16) * 72 + kc2 * 32 + quad * 8];
        Oa[nt] = __builtin_amdgcn_mfma_f32_16x16x32_bf16(pf[kc2], vf, Oa[nt], 0, 0, 0);
      }
  }
#pragma unroll
  for (int nt = 0; nt < 5; nt++)
#pragma unroll
    for (int r = 0; r < 4; r++){
      int row = q0 + wid * 16 + quad * 4 + r;
      int col = h * 80 + nt * 16 + l16;
      atomicAdd(&outAcc[(size_t)row * CDIM + col], Oa[nt][r] / lrow[r]);
    }
}

// ---------------- entity E1: P = exp(Q_e K_e^T) per (qtile, ktile), bf16, + rowsums
__global__ __launch_bounds__(256) void k_ent_qk(const unsigned short* __restrict__ proj,
                                                const int* __restrict__ labP,
                                                const int4* __restrict__ qtinfo,
                                                unsigned short* __restrict__ Sbuf,
                                                float* __restrict__ rowsum){
  int qt = blockIdx.y;
  int4 qi = qtinfo[qt];
  int nkt = (qi.y - qi.x) >> 7;
  if ((int)blockIdx.x >= nkt) return;
  int m0 = qt * 128, n0 = qi.x + blockIdx.x * 128;
  __shared__ __align__(16) unsigned short As[128 * 40];
  __shared__ __align__(16) unsigned short Bs[128 * 40];
  __shared__ int lQ[128], lK[128];
  int tid = threadIdx.x, wid = tid >> 6, lane = tid & 63;
  int quad = lane >> 4, l16 = lane & 15;
  int wm = (wid >> 1) * 64, wn = (wid & 1) * 64;
  if (tid < 128) lQ[tid] = labP[m0 + tid] & 0xff;
  else           lK[tid - 128] = labP[n0 + tid - 128] & 0xff;
  f32x4 acc[4][4];
#pragma unroll
  for (int i = 0; i < 4; i++)
#pragma unroll
    for (int j = 0; j < 4; j++) acc[i][j] = f32x4{0.f, 0.f, 0.f, 0.f};

  for (int k0 = 0; k0 < 640; k0 += 32){
    __syncthreads();
#pragma unroll
    for (int c = tid; c < 512; c += 256){
      int row = c >> 2, off = (c & 3) * 8;
      *(uint4*)(&As[row * 40 + off]) = *(const uint4*)(&proj[(size_t)(m0 + row) * NPROJ + 1920 + k0 + off]);
      *(uint4*)(&Bs[row * 40 + off]) = *(const uint4*)(&proj[(size_t)(n0 + row) * NPROJ + 2560 + k0 + off]);
    }
    __syncthreads();
    bf16x8 af[4], bfr[4];
#pragma unroll
    for (int t = 0; t < 4; t++){
      af[t]  = *(const bf16x8*)(&As[(wm + t * 16 + l16) * 40 + quad * 8]);
      bfr[t] = *(const bf16x8*)(&Bs[(wn + t * 16 + l16) * 40 + quad * 8]);
    }
#pragma unroll
    for (int mt = 0; mt < 4; mt++)
#pragma unroll
      for (int nt = 0; nt < 4; nt++)
        acc[mt][nt] = __builtin_amdgcn_mfma_f32_16x16x32_bf16(af[mt], bfr[nt], acc[mt][nt], 0, 0, 0);
  }
  unsigned short* St = Sbuf + ((size_t)(qi.z + blockIdx.x)) * 16384;
#pragma unroll
  for (int mt = 0; mt < 4; mt++)
#pragma unroll
    for (int r = 0; r < 4; r++){
      int lrow = wm + mt * 16 + quad * 4 + r;
      int myq = lQ[lrow];
      float psum = 0.f;
#pragma unroll
      for (int nt = 0; nt < 4; nt++){
        int lcol = wn + nt * 16 + l16;
        float p = (myq == lK[lcol]) ? __expf(acc[mt][nt][r]) : 0.f;
        St[lrow * 128 + lcol] = f2bf(p);
        psum += p;
      }
#pragma unroll
      for (int m = 1; m < 16; m <<= 1) psum += __shfl_xor(psum, m);
      if (l16 == 0) atomicAdd(&rowsum[m0 + lrow], psum);
    }
}

// ---------------- entity E2: attnS = bf16( P·V_e / rowsum + attnAcc )
__global__ __launch_bounds__(256) void k_ent_pv(const unsigned short* __restrict__ Sbuf,
                                                const unsigned short* __restrict__ veT,
                                                const int4* __restrict__ qtinfo,
                                                const float* __restrict__ rowsum,
                                                const float* __restrict__ attnAcc,
                                                unsigned short* __restrict__ attnS){
  int qt = blockIdx.y, d0 = blockIdx.x * 128;
  int4 qi = qtinfo[qt];
  int m0 = qt * 128;
  int nk = qi.y - qi.x;
  __shared__ __align__(16) unsigned short As[128 * 40];
  __shared__ __align__(16) unsigned short Bs[128 * 40];
  int tid = threadIdx.x, wid = tid >> 6, lane = tid & 63;
  int quad = lane >> 4, l16 = lane & 15;
  int wm = (wid >> 1) * 64, wn = (wid & 1) * 64;
  f32x4 acc[4][4];
#pragma unroll
  for (int i = 0; i < 4; i++)
#pragma unroll
    for (int j = 0; j < 4; j++) acc[i][j] = f32x4{0.f, 0.f, 0.f, 0.f};

  for (int kk = 0; kk < nk; kk += 32){
    const unsigned short* St = Sbuf + ((size_t)(qi.z + (kk >> 7))) * 16384;
    int kloc = kk & 127;
    __syncthreads();
#pragma unroll
    for (int c = tid; c < 512; c += 256){
      int row = c >> 2, off = (c & 3) * 8;
      *(uint4*)(&As[row * 40 + off]) = *(const uint4*)(&St[row * 128 + kloc + off]);
      *(uint4*)(&Bs[row * 40 + off]) = *(const uint4*)(&veT[(size_t)(d0 + row) * S_LEN + qi.x + kk + off]);
    }
    __syncthreads();
    bf16x8 af[4], bfr[4];
#pragma unroll
    for (int t = 0; t < 4; t++){
      af[t]  = *(const bf16x8*)(&As[(wm + t * 16 + l16) * 40 + quad * 8]);
      bfr[t] = *(const bf16x8*)(&Bs[(wn + t * 16 + l16) * 40 + quad * 8]);
    }
#pragma unroll
    for (int mt = 0; mt < 4; mt++)
#pragma unroll
      for (int nt = 0; nt < 4; nt++)
        acc[mt][nt] = __builtin_amdgcn_mfma_f32_16x16x32_bf16(af[mt], bfr[nt], acc[mt][nt], 0, 0, 0);
  }
#pragma unroll
  for (int mt = 0; mt < 4; mt++)
#pragma unroll
    for (int r = 0; r < 4; r++){
      int row = m0 + wm + mt * 16 + quad * 4 + r;
      float invL = 1.f / rowsum[row];
#pragma unroll
      for (int nt = 0; nt < 4; nt++){
        int col = d0 + wn + nt * 16 + l16;
        float v = acc[mt][nt][r] * invL + attnAcc[(size_t)row * CDIM + col];
        attnS[(size_t)row * CDIM + col] = f2bf(v);
      }
    }
}

extern "C" void kernel_launch(void* const* d_in, const int* in_sizes, int n_in,
                              void* d_out, int out_size, void* d_ws, size_t ws_size,
                              hipStream_t stream){
  const float* hs  = (const float*)d_in[0];
  const int* mask  = (const int*)d_in[1];
  const int* inp   = (const int*)d_in[2];
  char* ws = (char*)d_ws;
  int*            labels  = (int*)(ws + 0);
  int*            boff    = (int*)(ws + 16384);
  int*            cnt     = (int*)(ws + 16640);
  int*            perm    = (int*)(ws + 16896);
  int*            inv     = (int*)(ws + 33280);
  int*            labP    = (int*)(ws + 49664);
  int2*           tileR   = (int2*)(ws + 66048);
  int4*           qtinfo  = (int4*)(ws + 66560);
  float*          rowsum  = (float*)(ws + 67072);
  unsigned short* hsb     = (unsigned short*)(ws + 131072);
  unsigned short* Wall    = (unsigned short*)(ws + 5373952);
  unsigned short* proj    = (unsigned short*)(ws + 13565952);
  unsigned short* vT      = (unsigned short*)(ws + 60751872);
  float*          attnAcc = (float*)(ws + 76480512);
  unsigned short* Sbuf    = (unsigned short*)(ws + 86966272);   // up to 1024 tiles * 32 KB
  unsigned short* attnS   = (unsigned short*)(ws + 120520704);
  unsigned short* Wob     = Wall + 9 * 409600;

  k_labels<<<16, 256, 0, stream>>>(mask, inp, labels);
  k_hist<<<1, 256, 0, stream>>>(labels, boff, cnt);
  k_perm<<<16, 256, 0, stream>>>(labels, boff, cnt, perm, inv, labP);
  k_tiles<<<1, 256, 0, stream>>>(labP, boff, tileR, qtinfo, rowsum);
  k_cvt_hs<<<(S_LEN * CDIM / 4 + 255) / 256, 256, 0, stream>>>(hs, hsb, S_LEN * CDIM);
  WPtrs wp;
  for (int i = 0; i < 10; i++) wp.w[i] = (const float*)d_in[3 + i];
  k_cvt_w<<<(10 * 409600 / 4 + 255) / 256, 256, 0, stream>>>(wp, Wall);
  k_zero<<<(S_LEN * CDIM / 4 + 255) / 256, 256, 0, stream>>>((float4*)attnAcc, S_LEN * CDIM / 4);

  // all 9 projections in one GEMM, rows scattered into bucket-permuted order
  k_gemm<0><<<dim3(45, 32), 256, 0, stream>>>(hsb, Wall, S_LEN, NPROJ, CDIM, NPROJ,
                                              inv, proj, nullptr, nullptr);
  k_transpose_v<<<dim3(64, 10, 3), 256, 0, stream>>>(proj, vT);

  // branches 1+3 fused: z=0 orig (q,k,v), z=1 outside (q_o,k_o,v_o) with im==0 key gate
  k_attn80<<<dim3(64, 8, 2), 256, 0, stream>>>(proj, vT, labP, tileR, attnAcc);

  // branch 2 (entity, d=640): GEMM-ified, P materialized bf16 per bucket
  k_ent_qk<<<dim3(32, 32), 256, 0, stream>>>(proj, labP, qtinfo, Sbuf, rowsum);
  k_ent_pv<<<dim3(5, 32), 256, 0, stream>>>(Sbuf, vT + (size_t)1 * CDIM * S_LEN,
                                            qtinfo, rowsum, attnAcc, attnS);

  // out = attnS @ Wo^T + residual, un-permuted via perm in the epilogue
  k_gemm<1><<<dim3(5, 32), 256, 0, stream>>>(attnS, Wob, S_LEN, CDIM, CDIM, CDIM,
                                             perm, nullptr, (float*)d_out, hs);
}

// Round 5
// 509.752 us; speedup vs baseline: 2.0093x; 1.2012x over previous
//
#include <hip/hip_runtime.h>
#include <cstdint>

typedef __attribute__((ext_vector_type(8))) short bf16x8;
typedef __attribute__((ext_vector_type(4))) float f32x4;

#define S_LEN 4096
#define CDIM  640
#define NPROJ 5760

__device__ __forceinline__ unsigned short f2bf(float f){
  union { float f; uint32_t u; } v; v.f = f;
  uint32_t u = v.u;
  return (unsigned short)((u + 0x7fffu + ((u >> 16) & 1u)) >> 16);
}
__device__ __forceinline__ float b2f(unsigned short h){
  union { uint32_t u; float f; } v; v.u = ((uint32_t)h) << 16;
  return v.f;
}

// ---------------- labels: nearest-resize 512x512 -> 64x64, pack m | (im==0)<<8
__global__ void k_labels(const int* __restrict__ mask, const int* __restrict__ inp,
                         int* __restrict__ labels){
  int s = blockIdx.x * 256 + threadIdx.x;
  if (s >= S_LEN) return;
  int y = s >> 6, x = s & 63;
  int off = (y * 8) * 512 + x * 8;
  int m = mask[off] & 0xff;
  int o = (inp[off] == 0) ? 0x100 : 0;
  labels[s] = m | o;
}

// ---------------- bucket sort by label value (4 buckets)
__global__ void k_hist(const int* __restrict__ labels, int* __restrict__ boff, int* __restrict__ cnt){
  __shared__ int h[4];
  if (threadIdx.x < 4) h[threadIdx.x] = 0;
  __syncthreads();
  for (int s = threadIdx.x; s < S_LEN; s += 256) atomicAdd(&h[labels[s] & 3], 1);
  __syncthreads();
  if (threadIdx.x == 0){
    int a = 0;
    for (int c = 0; c < 4; c++){ boff[c] = a; a += h[c]; }
    boff[4] = a;
  }
  if (threadIdx.x < 4) cnt[threadIdx.x] = 0;
}

__global__ void k_perm(const int* __restrict__ labels, const int* __restrict__ boff,
                       int* __restrict__ cnt, int* __restrict__ perm,
                       int* __restrict__ inv, int* __restrict__ labP){
  int s = blockIdx.x * 256 + threadIdx.x;
  if (s >= S_LEN) return;
  int lab = labels[s];
  int c = lab & 3;
  int pos = boff[c] + atomicAdd(&cnt[c], 1);
  perm[pos] = s; inv[s] = pos; labP[pos] = lab;
}

// per 64-tile (attn80) and per 128-tile (entity) key ranges; zero rowsum
__global__ void k_tiles(const int* __restrict__ labP, const int* __restrict__ boff,
                        int2* __restrict__ tr, int4* __restrict__ qtinfo,
                        float* __restrict__ rowsum){
  int t = threadIdx.x;
  __shared__ int nkt[32];
  if (t < 64){
    int c0 = labP[t * 64] & 3, c1 = labP[t * 64 + 63] & 3;
    tr[t] = make_int2(boff[c0] & ~63, (boff[c1 + 1] + 63) & ~63);
  }
  if (t < 32){
    int c0 = labP[t * 128] & 3, c1 = labP[t * 128 + 127] & 3;
    int lo = boff[c0] & ~127, hi = (boff[c1 + 1] + 127) & ~127;
    qtinfo[t].x = lo; qtinfo[t].y = hi; qtinfo[t].w = 0;
    nkt[t] = (hi - lo) >> 7;
  }
  __syncthreads();
  if (t == 0){
    int a = 0;
    for (int i = 0; i < 32; i++){ qtinfo[i].z = a; a += nkt[i]; }
  }
  for (int s = t; s < S_LEN; s += 256) rowsum[s] = 0.f;
}

// ---------------- f32 -> bf16 converts
__global__ void k_cvt_hs(const float* __restrict__ src, unsigned short* __restrict__ dst, int n){
  int idx = (blockIdx.x * 256 + threadIdx.x) * 4;
  if (idx >= n) return;
  float4 v = *(const float4*)(src + idx);
  ushort4 o;
  o.x = f2bf(v.x); o.y = f2bf(v.y); o.z = f2bf(v.z); o.w = f2bf(v.w);
  *(ushort4*)(dst + idx) = o;
}

struct WPtrs { const float* w[10]; };

__global__ void k_cvt_w(WPtrs p, unsigned short* __restrict__ dst){
  int e = (blockIdx.x * 256 + threadIdx.x) * 4;
  if (e >= 10 * 409600) return;
  int a = e / 409600, r = e % 409600;
  float sc = (a == 0 || a == 6) ? 0.11180339887498948f   // 1/sqrt(80)
           : (a == 3 ? 0.03952847075210474f : 1.0f);     // 1/sqrt(640)
  float4 v = *(const float4*)(p.w[a] + r);
  ushort4 o;
  o.x = f2bf(v.x * sc); o.y = f2bf(v.y * sc); o.z = f2bf(v.z * sc); o.w = f2bf(v.w * sc);
  *(ushort4*)(dst + e) = o;
}

// ---------------- 128x128 MFMA GEMM: C[M,N] = A[M,K] * B[N,K]^T
template<int EPI>
__global__ __launch_bounds__(256) void k_gemm(const unsigned short* __restrict__ A,
                                              const unsigned short* __restrict__ B,
                                              int M, int N, int K, int ldc,
                                              const int* __restrict__ rowmap,
                                              unsigned short* __restrict__ Cb,
                                              float* __restrict__ Cf,
                                              const float* __restrict__ resid){
  __shared__ __align__(16) unsigned short As[128 * 40];
  __shared__ __align__(16) unsigned short Bs[128 * 40];
  int m0 = blockIdx.y * 128, n0 = blockIdx.x * 128;
  int tid = threadIdx.x;
  int wid = tid >> 6, lane = tid & 63;
  int quad = lane >> 4, l16 = lane & 15;
  int wm = (wid >> 1) * 64, wn = (wid & 1) * 64;
  f32x4 acc[4][4];
#pragma unroll
  for (int i = 0; i < 4; i++)
#pragma unroll
    for (int j = 0; j < 4; j++) acc[i][j] = f32x4{0.f, 0.f, 0.f, 0.f};

  for (int k0 = 0; k0 < K; k0 += 32){
    __syncthreads();
#pragma unroll
    for (int c = tid; c < 512; c += 256){
      int row = c >> 2, off = (c & 3) * 8;
      *(uint4*)(&As[row * 40 + off]) = *(const uint4*)(&A[(size_t)(m0 + row) * K + k0 + off]);
      *(uint4*)(&Bs[row * 40 + off]) = *(const uint4*)(&B[(size_t)(n0 + row) * K + k0 + off]);
    }
    __syncthreads();
    bf16x8 af[4], bfr[4];
#pragma unroll
    for (int t = 0; t < 4; t++){
      af[t]  = *(const bf16x8*)(&As[(wm + t * 16 + l16) * 40 + quad * 8]);
      bfr[t] = *(const bf16x8*)(&Bs[(wn + t * 16 + l16) * 40 + quad * 8]);
    }
#pragma unroll
    for (int mt = 0; mt < 4; mt++)
#pragma unroll
      for (int nt = 0; nt < 4; nt++)
        acc[mt][nt] = __builtin_amdgcn_mfma_f32_16x16x32_bf16(af[mt], bfr[nt], acc[mt][nt], 0, 0, 0);
  }
#pragma unroll
  for (int mt = 0; mt < 4; mt++)
#pragma unroll
    for (int nt = 0; nt < 4; nt++)
#pragma unroll
      for (int r = 0; r < 4; r++){
        int row = m0 + wm + mt * 16 + quad * 4 + r;
        int col = n0 + wn + nt * 16 + l16;
        float v = acc[mt][nt][r];
        if (EPI == 0){
          Cb[(size_t)rowmap[row] * ldc + col] = f2bf(v);
        } else {
          int ro = rowmap[row];
          Cf[(size_t)ro * ldc + col] = v + resid[(size_t)ro * ldc + col];
        }
      }
}

// ---------------- transpose the three V projections: vT[z][c][s] (permuted key index)
__global__ void k_transpose_v(const unsigned short* __restrict__ proj, unsigned short* __restrict__ vT){
  __shared__ unsigned short T[64][65];
  int z = blockIdx.z;
  int s0 = blockIdx.x * 64, c0 = blockIdx.y * 64;
  int colbase = 1280 + z * 1920 + c0;   // v:1280  v_e:3200  v_o:5120
  unsigned short* dst = vT + (size_t)z * CDIM * S_LEN;
  int tid = threadIdx.x;
  for (int i = tid; i < 64 * 64; i += 256){
    int r = i >> 6, c = i & 63;
    T[r][c] = proj[(size_t)(s0 + r) * NPROJ + colbase + c];
  }
  __syncthreads();
  for (int i = tid; i < 64 * 64; i += 256){
    int c = i >> 6, r = i & 63;
    dst[(size_t)(c0 + c) * S_LEN + s0 + r] = T[r][c];
  }
}

// ---------------- flash attention, both d=80 branches (z=0: orig, z=1: outside)
// v3: no max-stabilization (P=exp(S), masked->0), per-lane deferred row-sum,
// 2 barriers/tile, plain bf16-plane stores (no atomics).
__global__ __launch_bounds__(256) void k_attn80(const unsigned short* __restrict__ proj,
                                                const unsigned short* __restrict__ vT,
                                                const int* __restrict__ labP,
                                                const int2* __restrict__ tileRange,
                                                unsigned short* __restrict__ outP){
  __shared__ __align__(16) unsigned short Ks[64 * 104];
  __shared__ __align__(16) unsigned short Ps[64 * 72];
  __shared__ __align__(16) unsigned short Vt[80 * 72];
  __shared__ int labk[64];
  int tid = threadIdx.x, wid = tid >> 6, lane = tid & 63;
  int quad = lane >> 4, l16 = lane & 15;
  int q0 = blockIdx.x * 64;
  int h  = blockIdx.y;
  bool OUTSIDE = (blockIdx.z == 1);
  int qc = (OUTSIDE ? 3840 : 0) + h * 80;
  int kc = (OUTSIDE ? 4480 : 640) + h * 80;
  const unsigned short* vTb = vT + (size_t)(OUTSIDE ? 2 : 0) * CDIM * S_LEN;
  int2 range = tileRange[blockIdx.x];
  int t0 = range.x >> 6, t1 = range.y >> 6;

  // zero the K d-padding cols [80,96) once (stays zero)
  for (int i = tid; i < 128; i += 256){
    int row = i >> 1, off = 80 + (i & 1) * 8;
    *(uint4*)&Ks[row * 104 + off] = make_uint4(0, 0, 0, 0);
  }
  // Q fragments straight from global (A-layout: row=l16, k=quad*8+j)
  int qrow = q0 + wid * 16 + l16;
  bf16x8 qf[3];
  qf[0] = *(const bf16x8*)&proj[(size_t)qrow * NPROJ + qc + quad * 8];
  qf[1] = *(const bf16x8*)&proj[(size_t)qrow * NPROJ + qc + 32 + quad * 8];
  if (quad < 2) qf[2] = *(const bf16x8*)&proj[(size_t)qrow * NPROJ + qc + 64 + quad * 8];
  else          qf[2] = bf16x8{0, 0, 0, 0, 0, 0, 0, 0};

  int lq[4];
#pragma unroll
  for (int r = 0; r < 4; r++) lq[r] = labP[q0 + wid * 16 + quad * 4 + r] & 0xff;
  float lpart[4];
#pragma unroll
  for (int r = 0; r < 4; r++) lpart[r] = 0.f;
  f32x4 Oa[5];
#pragma unroll
  for (int t = 0; t < 5; t++) Oa[t] = f32x4{0.f, 0.f, 0.f, 0.f};

  // register prefetch state
  uint4 kpre[3], vpre[3];
  int labpre = 0;
  int kr[3], ko[3], vr[3], vo[3];
#pragma unroll
  for (int u = 0; u < 3; u++){
    int c = tid + u * 256;
    kr[u] = c / 10; ko[u] = (c % 10) * 8;
    vr[u] = c >> 3; vo[u] = (c & 7) * 8;
  }
#pragma unroll
  for (int u = 0; u < 3; u++){
    int c = tid + u * 256;
    if (c < 640){
      kpre[u] = *(const uint4*)&proj[(size_t)(t0 * 64 + kr[u]) * NPROJ + kc + ko[u]];
      vpre[u] = *(const uint4*)&vTb[(size_t)(h * 80 + vr[u]) * S_LEN + t0 * 64 + vo[u]];
    }
  }
  if (tid < 64) labpre = labP[t0 * 64 + tid];

  for (int kt = t0; kt < t1; kt++){
    __syncthreads();                       // prior tile's Ks/Vt reads done
#pragma unroll
    for (int u = 0; u < 3; u++){
      int c = tid + u * 256;
      if (c < 640){
        *(uint4*)&Ks[kr[u] * 104 + ko[u]] = kpre[u];
        *(uint4*)&Vt[vr[u] * 72 + vo[u]] = vpre[u];
      }
    }
    if (tid < 64) labk[tid] = labpre;
    __syncthreads();
    {
      int knext = (kt + 1 < t1) ? (kt + 1) * 64 : t0 * 64;
#pragma unroll
      for (int u = 0; u < 3; u++){
        int c = tid + u * 256;
        if (c < 640){
          kpre[u] = *(const uint4*)&proj[(size_t)(knext + kr[u]) * NPROJ + kc + ko[u]];
          vpre[u] = *(const uint4*)&vTb[(size_t)(h * 80 + vr[u]) * S_LEN + knext + vo[u]];
        }
      }
      if (tid < 64) labpre = labP[knext + tid];
    }

    // S = Q K^T (scale pre-folded into Wq)
    f32x4 sa[4];
#pragma unroll
    for (int nt = 0; nt < 4; nt++){
      f32x4 a = f32x4{0.f, 0.f, 0.f, 0.f};
#pragma unroll
      for (int dc = 0; dc < 3; dc++){
        bf16x8 kf = *(const bf16x8*)&Ks[(nt * 16 + l16) * 104 + dc * 32 + quad * 8];
        a = __builtin_amdgcn_mfma_f32_16x16x32_bf16(qf[dc], kf, a, 0, 0, 0);
      }
      sa[nt] = a;
    }
    // P = exp(S) masked; per-lane partial row-sums (no cross-lane work in-loop)
    int lk[4];
#pragma unroll
    for (int nt = 0; nt < 4; nt++) lk[nt] = labk[nt * 16 + l16];
#pragma unroll
    for (int r = 0; r < 4; r++){
#pragma unroll
      for (int nt = 0; nt < 4; nt++){
        bool valid = ((lk[nt] & 0xff) == lq[r]) && (!OUTSIDE || (lk[nt] & 0x100));
        float p = valid ? __expf(sa[nt][r]) : 0.f;
        lpart[r] += p;
        Ps[(wid * 16 + quad * 4 + r) * 72 + nt * 16 + l16] = f2bf(p);
      }
    }
    // Ps rows [wid*16, wid*16+16) are produced and consumed by this wave only
    // -> no barrier needed (within-wave lgkmcnt ordering suffices)
    bf16x8 pf[2];
#pragma unroll
    for (int kc2 = 0; kc2 < 2; kc2++)
      pf[kc2] = *(const bf16x8*)&Ps[(wid * 16 + l16) * 72 + kc2 * 32 + quad * 8];
#pragma unroll
    for (int kc2 = 0; kc2 < 2; kc2++)
#pragma unroll
      for (int nt = 0; nt < 5; nt++){
        bf16x8 vf = *(const bf16x8*)&Vt[(nt * 16 + l16) * 72 + kc2 * 32 + quad * 8];
        Oa[nt] = __builtin_amdgcn_mfma_f32_16x16x32_bf16(pf[kc2], vf, Oa[nt], 0, 0, 0);
      }
  }
  // row-sum reduce once, after the K loop
  float invL[4];
#pragma unroll
  for (int r = 0; r < 4; r++){
    float ps = lpart[r];
#pragma unroll
    for (int m = 1; m < 16; m <<= 1) ps += __shfl_xor(ps, m);
    invL[r] = 1.f / ps;
  }
  unsigned short* dst = outP + (size_t)blockIdx.z * S_LEN * CDIM;
#pragma unroll
  for (int nt = 0; nt < 5; nt++)
#pragma unroll
    for (int r = 0; r < 4; r++){
      int row = q0 + wid * 16 + quad * 4 + r;
      int col = h * 80 + nt * 16 + l16;
      dst[(size_t)row * CDIM + col] = f2bf(Oa[nt][r] * invL[r]);
    }
}

// ---------------- entity E1: P = exp(Q_e K_e^T) per (qtile, ktile), bf16, + rowsums
__global__ __launch_bounds__(256) void k_ent_qk(const unsigned short* __restrict__ proj,
                                                const int* __restrict__ labP,
                                                const int4* __restrict__ qtinfo,
                                                unsigned short* __restrict__ Sbuf,
                                                float* __restrict__ rowsum){
  int qt = blockIdx.y;
  int4 qi = qtinfo[qt];
  int nkt = (qi.y - qi.x) >> 7;
  if ((int)blockIdx.x >= nkt) return;
  int m0 = qt * 128, n0 = qi.x + blockIdx.x * 128;
  __shared__ __align__(16) unsigned short As[128 * 40];
  __shared__ __align__(16) unsigned short Bs[128 * 40];
  __shared__ int lQ[128], lK[128];
  int tid = threadIdx.x, wid = tid >> 6, lane = tid & 63;
  int quad = lane >> 4, l16 = lane & 15;
  int wm = (wid >> 1) * 64, wn = (wid & 1) * 64;
  if (tid < 128) lQ[tid] = labP[m0 + tid] & 0xff;
  else           lK[tid - 128] = labP[n0 + tid - 128] & 0xff;
  f32x4 acc[4][4];
#pragma unroll
  for (int i = 0; i < 4; i++)
#pragma unroll
    for (int j = 0; j < 4; j++) acc[i][j] = f32x4{0.f, 0.f, 0.f, 0.f};

  for (int k0 = 0; k0 < 640; k0 += 32){
    __syncthreads();
#pragma unroll
    for (int c = tid; c < 512; c += 256){
      int row = c >> 2, off = (c & 3) * 8;
      *(uint4*)(&As[row * 40 + off]) = *(const uint4*)(&proj[(size_t)(m0 + row) * NPROJ + 1920 + k0 + off]);
      *(uint4*)(&Bs[row * 40 + off]) = *(const uint4*)(&proj[(size_t)(n0 + row) * NPROJ + 2560 + k0 + off]);
    }
    __syncthreads();
    bf16x8 af[4], bfr[4];
#pragma unroll
    for (int t = 0; t < 4; t++){
      af[t]  = *(const bf16x8*)(&As[(wm + t * 16 + l16) * 40 + quad * 8]);
      bfr[t] = *(const bf16x8*)(&Bs[(wn + t * 16 + l16) * 40 + quad * 8]);
    }
#pragma unroll
    for (int mt = 0; mt < 4; mt++)
#pragma unroll
      for (int nt = 0; nt < 4; nt++)
        acc[mt][nt] = __builtin_amdgcn_mfma_f32_16x16x32_bf16(af[mt], bfr[nt], acc[mt][nt], 0, 0, 0);
  }
  unsigned short* St = Sbuf + ((size_t)(qi.z + blockIdx.x)) * 16384;
#pragma unroll
  for (int mt = 0; mt < 4; mt++)
#pragma unroll
    for (int r = 0; r < 4; r++){
      int lrow = wm + mt * 16 + quad * 4 + r;
      int myq = lQ[lrow];
      float psum = 0.f;
#pragma unroll
      for (int nt = 0; nt < 4; nt++){
        int lcol = wn + nt * 16 + l16;
        float p = (myq == lK[lcol]) ? __expf(acc[mt][nt][r]) : 0.f;
        St[lrow * 128 + lcol] = f2bf(p);
        psum += p;
      }
#pragma unroll
      for (int m = 1; m < 16; m <<= 1) psum += __shfl_xor(psum, m);
      if (l16 == 0) atomicAdd(&rowsum[m0 + lrow], psum);
    }
}

// ---------------- entity E2: attnS = bf16( P·V_e / rowsum + plane0 + plane1 )
__global__ __launch_bounds__(256) void k_ent_pv(const unsigned short* __restrict__ Sbuf,
                                                const unsigned short* __restrict__ veT,
                                                const int4* __restrict__ qtinfo,
                                                const float* __restrict__ rowsum,
                                                const unsigned short* __restrict__ planes,
                                                unsigned short* __restrict__ attnS){
  int qt = blockIdx.y, d0 = blockIdx.x * 128;
  int4 qi = qtinfo[qt];
  int m0 = qt * 128;
  int nk = qi.y - qi.x;
  __shared__ __align__(16) unsigned short As[128 * 40];
  __shared__ __align__(16) unsigned short Bs[128 * 40];
  int tid = threadIdx.x, wid = tid >> 6, lane = tid & 63;
  int quad = lane >> 4, l16 = lane & 15;
  int wm = (wid >> 1) * 64, wn = (wid & 1) * 64;
  f32x4 acc[4][4];
#pragma unroll
  for (int i = 0; i < 4; i++)
#pragma unroll
    for (int j = 0; j < 4; j++) acc[i][j] = f32x4{0.f, 0.f, 0.f, 0.f};

  for (int kk = 0; kk < nk; kk += 32){
    const unsigned short* St = Sbuf + ((size_t)(qi.z + (kk >> 7))) * 16384;
    int kloc = kk & 127;
    __syncthreads();
#pragma unroll
    for (int c = tid; c < 512; c += 256){
      int row = c >> 2, off = (c & 3) * 8;
      *(uint4*)(&As[row * 40 + off]) = *(const uint4*)(&St[row * 128 + kloc + off]);
      *(uint4*)(&Bs[row * 40 + off]) = *(const uint4*)(&veT[(size_t)(d0 + row) * S_LEN + qi.x + kk + off]);
    }
    __syncthreads();
    bf16x8 af[4], bfr[4];
#pragma unroll
    for (int t = 0; t < 4; t++){
      af[t]  = *(const bf16x8*)(&As[(wm + t * 16 + l16) * 40 + quad * 8]);
      bfr[t] = *(const bf16x8*)(&Bs[(wn + t * 16 + l16) * 40 + quad * 8]);
    }
#pragma unroll
    for (int mt = 0; mt < 4; mt++)
#pragma unroll
      for (int nt = 0; nt < 4; nt++)
        acc[mt][nt] = __builtin_amdgcn_mfma_f32_16x16x32_bf16(af[mt], bfr[nt], acc[mt][nt], 0, 0, 0);
  }
#pragma unroll
  for (int mt = 0; mt < 4; mt++)
#pragma unroll
    for (int r = 0; r < 4; r++){
      int row = m0 + wm + mt * 16 + quad * 4 + r;
      float invL = 1.f / rowsum[row];
#pragma unroll
      for (int nt = 0; nt < 4; nt++){
        int col = d0 + wn + nt * 16 + l16;
        size_t idx = (size_t)row * CDIM + col;
        float v = acc[mt][nt][r] * invL + b2f(planes[idx]) + b2f(planes[(size_t)S_LEN * CDIM + idx]);
        attnS[idx] = f2bf(v);
      }
    }
}

extern "C" void kernel_launch(void* const* d_in, const int* in_sizes, int n_in,
                              void* d_out, int out_size, void* d_ws, size_t ws_size,
                              hipStream_t stream){
  const float* hs  = (const float*)d_in[0];
  const int* mask  = (const int*)d_in[1];
  const int* inp   = (const int*)d_in[2];
  char* ws = (char*)d_ws;
  int*            labels  = (int*)(ws + 0);
  int*            boff    = (int*)(ws + 16384);
  int*            cnt     = (int*)(ws + 16640);
  int*            perm    = (int*)(ws + 16896);
  int*            inv     = (int*)(ws + 33280);
  int*            labP    = (int*)(ws + 49664);
  int2*           tileR   = (int2*)(ws + 66048);
  int4*           qtinfo  = (int4*)(ws + 66560);
  float*          rowsum  = (float*)(ws + 67072);
  unsigned short* hsb     = (unsigned short*)(ws + 131072);
  unsigned short* Wall    = (unsigned short*)(ws + 5373952);
  unsigned short* proj    = (unsigned short*)(ws + 13565952);
  unsigned short* vT      = (unsigned short*)(ws + 60751872);
  unsigned short* planes  = (unsigned short*)(ws + 76480512);   // 2 bf16 planes = 10.5 MB
  unsigned short* Sbuf    = (unsigned short*)(ws + 86966272);   // up to 1024 tiles * 32 KB
  unsigned short* attnS   = (unsigned short*)(ws + 120520704);
  unsigned short* Wob     = Wall + 9 * 409600;

  k_labels<<<16, 256, 0, stream>>>(mask, inp, labels);
  k_hist<<<1, 256, 0, stream>>>(labels, boff, cnt);
  k_perm<<<16, 256, 0, stream>>>(labels, boff, cnt, perm, inv, labP);
  k_tiles<<<1, 256, 0, stream>>>(labP, boff, tileR, qtinfo, rowsum);
  k_cvt_hs<<<(S_LEN * CDIM / 4 + 255) / 256, 256, 0, stream>>>(hs, hsb, S_LEN * CDIM);
  WPtrs wp;
  for (int i = 0; i < 10; i++) wp.w[i] = (const float*)d_in[3 + i];
  k_cvt_w<<<(10 * 409600 / 4 + 255) / 256, 256, 0, stream>>>(wp, Wall);

  // all 9 projections in one GEMM, rows scattered into bucket-permuted order
  k_gemm<0><<<dim3(45, 32), 256, 0, stream>>>(hsb, Wall, S_LEN, NPROJ, CDIM, NPROJ,
                                              inv, proj, nullptr, nullptr);
  k_transpose_v<<<dim3(64, 10, 3), 256, 0, stream>>>(proj, vT);

  // branches 1+3 fused: z=0 orig (q,k,v), z=1 outside (q_o,k_o,v_o) with im==0 key gate
  k_attn80<<<dim3(64, 8, 2), 256, 0, stream>>>(proj, vT, labP, tileR, planes);

  // branch 2 (entity, d=640): GEMM-ified, P materialized bf16 per bucket
  k_ent_qk<<<dim3(32, 32), 256, 0, stream>>>(proj, labP, qtinfo, Sbuf, rowsum);
  k_ent_pv<<<dim3(5, 32), 256, 0, stream>>>(Sbuf, vT + (size_t)1 * CDIM * S_LEN,
                                            qtinfo, rowsum, planes, attnS);

  // out = attnS @ Wo^T + residual, un-permuted via perm in the epilogue
  k_gemm<1><<<dim3(5, 32), 256, 0, stream>>>(attnS, Wob, S_LEN, CDIM, CDIM, CDIM,
                                             perm, nullptr, (float*)d_out, hs);
}